// Round 1
// baseline (9179.765 us; speedup 1.0000x reference)
//
#include <hip/hip_runtime.h>
#include <math.h>

#define B_ 8
#define N_ 4096
#define D_ 6
#define K_ 64
#define NS1_ 2048
#define NS2_ 512

// ---------- helpers ----------

__device__ __forceinline__ float dist2_rn(const float* __restrict__ a, const float* __restrict__ q) {
    // exact np semantics: sequential sum of (a-b)^2, round-to-nearest each op, no fma
    float s = 0.f;
#pragma unroll
    for (int d = 0; d < 6; ++d) {
        float diff = __fsub_rn(a[d], q[d]);
        s = __fadd_rn(s, __fmul_rn(diff, diff));
    }
    return s;
}

__device__ __forceinline__ unsigned mapf(float x) {
    unsigned u = __float_as_uint(x);
    return (u & 0x80000000u) ? ~u : (u | 0x80000000u);
}
__device__ __forceinline__ float unmapf(unsigned u) {
    return __uint_as_float((u & 0x80000000u) ? (u & 0x7FFFFFFFu) : ~u);
}

// ---------- FPS: one block per cloud, 1024 threads ----------
// matches jnp: idx[0]=0; d0 = dist to p0; repeat: nxt=argmax(mind) (first occurrence), mind=min(mind,dist to nxt)

template <int P>
__global__ __launch_bounds__(1024) void fps_kernel(const float* __restrict__ pos, int* __restrict__ idx_out,
                                                   float* __restrict__ posq, int N, int ns) {
    int b = blockIdx.x, t = threadIdx.x;
    const float* p = pos + (size_t)b * N * 6;
    __shared__ float cur[6];
    __shared__ float swv[16];
    __shared__ int swi[16];
    __shared__ int snext;

    if (t == 0) idx_out[(size_t)b * ns] = 0;
    if (t < 6) {
        float c = p[t];
        cur[t] = c;
        posq[(size_t)b * ns * 6 + t] = c;
    }
    __syncthreads();

    float mind[P];
#pragma unroll
    for (int i = 0; i < P; ++i) {
        int j = t + i * 1024;
        mind[i] = dist2_rn(p + (size_t)j * 6, cur);
    }

    for (int s = 1; s < ns; ++s) {
        // local argmax (ascending index, strict > keeps lowest index)
        float bv = -1.f;
        int bi = 0;
#pragma unroll
        for (int i = 0; i < P; ++i) {
            if (mind[i] > bv) { bv = mind[i]; bi = t + i * 1024; }
        }
        // wave reduce (64 lanes)
#pragma unroll
        for (int off = 32; off > 0; off >>= 1) {
            float ov = __shfl_down(bv, off, 64);
            int oi = __shfl_down(bi, off, 64);
            if (ov > bv || (ov == bv && oi < bi)) { bv = ov; bi = oi; }
        }
        int w = t >> 6;
        if ((t & 63) == 0) { swv[w] = bv; swi[w] = bi; }
        __syncthreads();
        if (t == 0) {
            float fv = swv[0];
            int fi = swi[0];
            for (int k = 1; k < 16; ++k) {
                if (swv[k] > fv || (swv[k] == fv && swi[k] < fi)) { fv = swv[k]; fi = swi[k]; }
            }
            snext = fi;
            idx_out[(size_t)b * ns + s] = fi;
        }
        __syncthreads();
        if (t < 6) {
            float c = p[(size_t)snext * 6 + t];
            cur[t] = c;
            posq[((size_t)b * ns + s) * 6 + t] = c;
        }
        __syncthreads();
#pragma unroll
        for (int i = 0; i < P; ++i) {
            int j = t + i * 1024;
            float d2 = dist2_rn(p + (size_t)j * 6, cur);
            mind[i] = fminf(mind[i], d2);
        }
    }
}

// ---------- ball query: one thread per query, block=64 ----------
// keeps K smallest d2 within r2, stable ties (lower source index first) -> matches lax.top_k set

__global__ __launch_bounds__(64) void ball_kernel(const float* __restrict__ pos, const float* __restrict__ posq,
                                                  int* __restrict__ nbr, int* __restrict__ cnt,
                                                  int N, int nq, float r2) {
    __shared__ float sd[64 * K_];
    __shared__ int si[64 * K_];
    int qid = blockIdx.x * 64 + threadIdx.x;
    int b = qid / nq;
    int base = threadIdx.x * K_;
    const float* p = pos + (size_t)b * N * 6;
    float q[6];
#pragma unroll
    for (int d = 0; d < 6; ++d) q[d] = posq[(size_t)qid * 6 + d];

    int n = 0;
    for (int j = 0; j < N; ++j) {
        float d2 = dist2_rn(p + (size_t)j * 6, q);
        if (d2 <= r2) {
            if (n < K_) {
                int i = n++;
                while (i > 0 && sd[base + i - 1] > d2) {
                    sd[base + i] = sd[base + i - 1];
                    si[base + i] = si[base + i - 1];
                    --i;
                }
                sd[base + i] = d2;
                si[base + i] = j;
            } else if (d2 < sd[base + K_ - 1]) {
                int i = K_ - 1;
                while (i > 0 && sd[base + i - 1] > d2) {
                    sd[base + i] = sd[base + i - 1];
                    si[base + i] = si[base + i - 1];
                    --i;
                }
                sd[base + i] = d2;
                si[base + i] = j;
            }
        }
    }
    cnt[qid] = n;
    for (int i = 0; i < n; ++i) nbr[(size_t)qid * K_ + i] = si[base + i];
}

// ---------- SA1 conv: one wave per query; MLP 6->64->64->128, max over valid neighbors ----------

__global__ __launch_bounds__(256) void sa1_conv(const float* __restrict__ pos, const float* __restrict__ posq,
                                                const int* __restrict__ nbr, const int* __restrict__ cnt,
                                                const float* __restrict__ W1, const float* __restrict__ B1,
                                                const float* __restrict__ W2, const float* __restrict__ B2,
                                                const float* __restrict__ W3, const float* __restrict__ B3,
                                                float* __restrict__ out, int N, int nq) {
    int lane = threadIdx.x & 63;
    int w = threadIdx.x >> 6;
    int qid = blockIdx.x * 4 + w;
    int b = qid / nq;
    const float* p = pos + (size_t)b * N * 6;
    float q[6];
#pragma unroll
    for (int d = 0; d < 6; ++d) q[d] = posq[(size_t)qid * 6 + d];
    int c = cnt[qid];
    float m0 = -INFINITY, m1 = -INFINITY;

    for (int n = 0; n < c; ++n) {
        int j = nbr[(size_t)qid * K_ + n];
        float rel[6];
#pragma unroll
        for (int d = 0; d < 6; ++d) rel[d] = p[(size_t)j * 6 + d] - q[d];
        // L1: 6 -> 64 (lane = out channel)
        float a = B1[lane];
#pragma unroll
        for (int d = 0; d < 6; ++d) a = fmaf(W1[d * 64 + lane], rel[d], a);
        float h1 = fmaxf(a, 0.f);
        // L2: 64 -> 64
        float a2 = B2[lane];
        for (int k = 0; k < 64; ++k) {
            float v = __shfl(h1, k, 64);
            a2 = fmaf(W2[k * 64 + lane], v, a2);
        }
        float h2 = fmaxf(a2, 0.f);
        // L3: 64 -> 128 (lane, lane+64)
        float o0 = B3[lane], o1 = B3[64 + lane];
        for (int k = 0; k < 64; ++k) {
            float v = __shfl(h2, k, 64);
            o0 = fmaf(W3[k * 128 + lane], v, o0);
            o1 = fmaf(W3[k * 128 + 64 + lane], v, o1);
        }
        m0 = fmaxf(m0, o0);
        m1 = fmaxf(m1, o1);
    }
    out[(size_t)qid * 128 + lane] = m0;
    out[(size_t)qid * 128 + 64 + lane] = m1;
}

// ---------- SA2 conv: one wave per query; feat=[x1(128), rel(6)] -> 128 -> 128 -> 256 ----------

__global__ __launch_bounds__(256) void sa2_conv(const float* __restrict__ pos1, const float* __restrict__ posq,
                                                const int* __restrict__ nbr, const int* __restrict__ cnt,
                                                const float* __restrict__ x1,
                                                const float* __restrict__ W1, const float* __restrict__ B1,
                                                const float* __restrict__ W2, const float* __restrict__ B2,
                                                const float* __restrict__ W3, const float* __restrict__ B3,
                                                float* __restrict__ out) {
    int lane = threadIdx.x & 63;
    int w = threadIdx.x >> 6;
    int qid = blockIdx.x * 4 + w;
    int b = qid / NS2_;
    float q[6];
#pragma unroll
    for (int d = 0; d < 6; ++d) q[d] = posq[(size_t)qid * 6 + d];
    int c = cnt[qid];
    float m0 = -INFINITY, m1 = -INFINITY, m2 = -INFINITY, m3 = -INFINITY;

    for (int n = 0; n < c; ++n) {
        int j = nbr[(size_t)qid * K_ + n];
        size_t row = (size_t)b * NS1_ + j;
        const float* xs = x1 + row * 128;
        float rel[6];
#pragma unroll
        for (int d = 0; d < 6; ++d) rel[d] = pos1[row * 6 + d] - q[d];
        // L1: 134 -> 128 (lane, lane+64)
        float a0 = B1[lane], a1 = B1[64 + lane];
        for (int k = 0; k < 128; ++k) {
            float v = xs[k];
            a0 = fmaf(W1[k * 128 + lane], v, a0);
            a1 = fmaf(W1[k * 128 + 64 + lane], v, a1);
        }
#pragma unroll
        for (int d = 0; d < 6; ++d) {
            float v = rel[d];
            a0 = fmaf(W1[(128 + d) * 128 + lane], v, a0);
            a1 = fmaf(W1[(128 + d) * 128 + 64 + lane], v, a1);
        }
        float h1a = fmaxf(a0, 0.f), h1b = fmaxf(a1, 0.f);
        // L2: 128 -> 128
        float c0 = B2[lane], c1 = B2[64 + lane];
        for (int k = 0; k < 64; ++k) {
            float v = __shfl(h1a, k, 64);
            c0 = fmaf(W2[k * 128 + lane], v, c0);
            c1 = fmaf(W2[k * 128 + 64 + lane], v, c1);
        }
        for (int k = 0; k < 64; ++k) {
            float v = __shfl(h1b, k, 64);
            c0 = fmaf(W2[(64 + k) * 128 + lane], v, c0);
            c1 = fmaf(W2[(64 + k) * 128 + 64 + lane], v, c1);
        }
        float h2a = fmaxf(c0, 0.f), h2b = fmaxf(c1, 0.f);
        // L3: 128 -> 256 (lane + 64u)
        float e0 = B3[lane], e1 = B3[64 + lane], e2 = B3[128 + lane], e3 = B3[192 + lane];
        for (int k = 0; k < 64; ++k) {
            float v = __shfl(h2a, k, 64);
            e0 = fmaf(W3[k * 256 + lane], v, e0);
            e1 = fmaf(W3[k * 256 + 64 + lane], v, e1);
            e2 = fmaf(W3[k * 256 + 128 + lane], v, e2);
            e3 = fmaf(W3[k * 256 + 192 + lane], v, e3);
        }
        for (int k = 0; k < 64; ++k) {
            float v = __shfl(h2b, k, 64);
            e0 = fmaf(W3[(64 + k) * 256 + lane], v, e0);
            e1 = fmaf(W3[(64 + k) * 256 + 64 + lane], v, e1);
            e2 = fmaf(W3[(64 + k) * 256 + 128 + lane], v, e2);
            e3 = fmaf(W3[(64 + k) * 256 + 192 + lane], v, e3);
        }
        m0 = fmaxf(m0, e0);
        m1 = fmaxf(m1, e1);
        m2 = fmaxf(m2, e2);
        m3 = fmaxf(m3, e3);
    }
    out[(size_t)qid * 256 + lane] = m0;
    out[(size_t)qid * 256 + 64 + lane] = m1;
    out[(size_t)qid * 256 + 128 + lane] = m2;
    out[(size_t)qid * 256 + 192 + lane] = m3;
}

// ---------- init g ----------

__global__ void init_g(unsigned* __restrict__ g) {
    g[blockIdx.x * 1024 + threadIdx.x] = 0u;
}

// ---------- MLP3 + global max: grid (8,16), block 256; wave handles 8 queries ----------

__global__ __launch_bounds__(256) void mlp3_kernel(const float* __restrict__ x2, const float* __restrict__ pos2,
                                                   const float* __restrict__ W0, const float* __restrict__ B0,
                                                   const float* __restrict__ W1, const float* __restrict__ B1,
                                                   const float* __restrict__ W2, const float* __restrict__ B2,
                                                   unsigned* __restrict__ g) {
    int lane = threadIdx.x & 63;
    int w = threadIdx.x >> 6;
    int b = blockIdx.x;
    int qbase = blockIdx.y * 32 + w * 8;
    __shared__ float sm[4][1024];

    float me[16];
#pragma unroll
    for (int u = 0; u < 16; ++u) me[u] = -INFINITY;

    for (int qi = 0; qi < 8; ++qi) {
        int qid = b * NS2_ + qbase + qi;
        const float* xin = x2 + (size_t)qid * 256;
        // L1: 262 -> 256, 4 per lane
        float a_[4];
#pragma unroll
        for (int u = 0; u < 4; ++u) a_[u] = B0[lane + 64 * u];
        for (int k = 0; k < 256; ++k) {
            float v = xin[k];
#pragma unroll
            for (int u = 0; u < 4; ++u) a_[u] = fmaf(W0[k * 256 + lane + 64 * u], v, a_[u]);
        }
#pragma unroll
        for (int d = 0; d < 6; ++d) {
            float v = pos2[(size_t)qid * 6 + d];
#pragma unroll
            for (int u = 0; u < 4; ++u) a_[u] = fmaf(W0[(256 + d) * 256 + lane + 64 * u], v, a_[u]);
        }
        float h1_[4];
#pragma unroll
        for (int u = 0; u < 4; ++u) h1_[u] = fmaxf(a_[u], 0.f);
        // L2: 256 -> 512, 8 per lane
        float c_[8];
#pragma unroll
        for (int u = 0; u < 8; ++u) c_[u] = B1[lane + 64 * u];
#pragma unroll
        for (int ch = 0; ch < 4; ++ch) {
            float hv = h1_[ch];
            for (int k2 = 0; k2 < 64; ++k2) {
                float v = __shfl(hv, k2, 64);
                int k = ch * 64 + k2;
#pragma unroll
                for (int u = 0; u < 8; ++u) c_[u] = fmaf(W1[(size_t)k * 512 + lane + 64 * u], v, c_[u]);
            }
        }
        float h2_[8];
#pragma unroll
        for (int u = 0; u < 8; ++u) h2_[u] = fmaxf(c_[u], 0.f);
        // L3: 512 -> 1024, 16 per lane
        float e_[16];
#pragma unroll
        for (int u = 0; u < 16; ++u) e_[u] = B2[lane + 64 * u];
#pragma unroll
        for (int ch = 0; ch < 8; ++ch) {
            float hv = h2_[ch];
            for (int k2 = 0; k2 < 64; ++k2) {
                float v = __shfl(hv, k2, 64);
                int k = ch * 64 + k2;
#pragma unroll
                for (int u = 0; u < 16; ++u) e_[u] = fmaf(W2[(size_t)k * 1024 + lane + 64 * u], v, e_[u]);
            }
        }
#pragma unroll
        for (int u = 0; u < 16; ++u) me[u] = fmaxf(me[u], e_[u]);
    }

#pragma unroll
    for (int u = 0; u < 16; ++u) sm[w][lane + 64 * u] = me[u];
    __syncthreads();
    if (w == 0) {
#pragma unroll
        for (int u = 0; u < 16; ++u) {
            int ch = lane + 64 * u;
            float v = fmaxf(fmaxf(sm[0][ch], sm[1][ch]), fmaxf(sm[2][ch], sm[3][ch]));
            atomicMax(&g[b * 1024 + ch], mapf(v));
        }
    }
}

// ---------- MLP4: 1024 -> 512 (relu) -> 512; one block per b ----------

__global__ __launch_bounds__(512) void mlp4_kernel(const unsigned* __restrict__ g,
                                                   const float* __restrict__ W0, const float* __restrict__ B0,
                                                   const float* __restrict__ W1, const float* __restrict__ B1,
                                                   float* __restrict__ out) {
    int b = blockIdx.x;
    int c = threadIdx.x;
    __shared__ float h[512];
    float a = B0[c];
    for (int k = 0; k < 1024; ++k) {
        float v = unmapf(g[b * 1024 + k]);
        a = fmaf(v, W0[k * 512 + c], a);
    }
    h[c] = fmaxf(a, 0.f);
    __syncthreads();
    float o = B1[c];
    for (int k = 0; k < 512; ++k) o = fmaf(h[k], W1[k * 512 + c], o);
    out[(size_t)b * 512 + c] = o;
}

// ---------- launch ----------

extern "C" void kernel_launch(void* const* d_in, const int* in_sizes, int n_in,
                              void* d_out, int out_size, void* d_ws, size_t ws_size,
                              hipStream_t stream) {
    const float* pos = (const float*)d_in[0];  // [B*N, 6]
    const float* w1_0 = (const float*)d_in[3];
    const float* b1_0 = (const float*)d_in[4];
    const float* w1_1 = (const float*)d_in[5];
    const float* b1_1 = (const float*)d_in[6];
    const float* w1_2 = (const float*)d_in[7];
    const float* b1_2 = (const float*)d_in[8];
    const float* w2_0 = (const float*)d_in[9];
    const float* b2_0 = (const float*)d_in[10];
    const float* w2_1 = (const float*)d_in[11];
    const float* b2_1 = (const float*)d_in[12];
    const float* w2_2 = (const float*)d_in[13];
    const float* b2_2 = (const float*)d_in[14];
    const float* w3_0 = (const float*)d_in[15];
    const float* b3_0 = (const float*)d_in[16];
    const float* w3_1 = (const float*)d_in[17];
    const float* b3_1 = (const float*)d_in[18];
    const float* w3_2 = (const float*)d_in[19];
    const float* b3_2 = (const float*)d_in[20];
    const float* w4_0 = (const float*)d_in[21];
    const float* b4_0 = (const float*)d_in[22];
    const float* w4_1 = (const float*)d_in[23];
    const float* b4_1 = (const float*)d_in[24];
    float* out = (float*)d_out;

    char* ws = (char*)d_ws;
    size_t off = 0;
    int* idx1 = (int*)(ws + off);      off += (size_t)B_ * NS1_ * 4;            // 64 KB
    float* pos1 = (float*)(ws + off);  off += (size_t)B_ * NS1_ * 6 * 4;        // 384 KB
    int* nbr1 = (int*)(ws + off);      off += (size_t)B_ * NS1_ * K_ * 4;       // 4 MB
    int* cnt1 = (int*)(ws + off);      off += (size_t)B_ * NS1_ * 4;            // 64 KB
    float* x1 = (float*)(ws + off);    off += (size_t)B_ * NS1_ * 128 * 4;      // 8 MB
    int* idx2 = (int*)(ws + off);      off += (size_t)B_ * NS2_ * 4;
    float* pos2 = (float*)(ws + off);  off += (size_t)B_ * NS2_ * 6 * 4;
    int* nbr2 = (int*)(ws + off);      off += (size_t)B_ * NS2_ * K_ * 4;       // 1 MB
    int* cnt2 = (int*)(ws + off);      off += (size_t)B_ * NS2_ * 4;
    float* x2 = (float*)(ws + off);    off += (size_t)B_ * NS2_ * 256 * 4;      // 4 MB
    unsigned* g = (unsigned*)(ws + off); off += (size_t)B_ * 1024 * 4;

    const float r2_1 = (float)(0.2 * 0.2);
    const float r2_2 = (float)(0.4 * 0.4);

    // SA1
    fps_kernel<4><<<B_, 1024, 0, stream>>>(pos, idx1, pos1, N_, NS1_);
    ball_kernel<<<(B_ * NS1_) / 64, 64, 0, stream>>>(pos, pos1, nbr1, cnt1, N_, NS1_, r2_1);
    sa1_conv<<<(B_ * NS1_) / 4, 256, 0, stream>>>(pos, pos1, nbr1, cnt1,
                                                  w1_0, b1_0, w1_1, b1_1, w1_2, b1_2, x1, N_, NS1_);
    // SA2
    fps_kernel<2><<<B_, 1024, 0, stream>>>(pos1, idx2, pos2, NS1_, NS2_);
    ball_kernel<<<(B_ * NS2_) / 64, 64, 0, stream>>>(pos1, pos2, nbr2, cnt2, NS1_, NS2_, r2_2);
    sa2_conv<<<(B_ * NS2_) / 4, 256, 0, stream>>>(pos1, pos2, nbr2, cnt2, x1,
                                                  w2_0, b2_0, w2_1, b2_1, w2_2, b2_2, x2);
    // MLP3 + global max
    init_g<<<B_, 1024, 0, stream>>>(g);
    mlp3_kernel<<<dim3(B_, 16), 256, 0, stream>>>(x2, pos2, w3_0, b3_0, w3_1, b3_1, w3_2, b3_2, g);
    // MLP4
    mlp4_kernel<<<B_, 512, 0, stream>>>(g, w4_0, b4_0, w4_1, b4_1, out);
}

// Round 2
// 6987.511 us; speedup vs baseline: 1.3137x; 1.3137x over previous
//
#include <hip/hip_runtime.h>
#include <math.h>

#define B_ 8
#define N_ 4096
#define D_ 6
#define K_ 64
#define NS1_ 2048
#define NS2_ 512

// ---------- helpers ----------

__device__ __forceinline__ float dist2_rn(const float* __restrict__ a, const float* __restrict__ q) {
    // exact np semantics: sequential sum of (a-b)^2, round-to-nearest each op, no fma
    float s = 0.f;
#pragma unroll
    for (int d = 0; d < 6; ++d) {
        float diff = __fsub_rn(a[d], q[d]);
        s = __fadd_rn(s, __fmul_rn(diff, diff));
    }
    return s;
}

__device__ __forceinline__ unsigned mapf(float x) {
    unsigned u = __float_as_uint(x);
    return (u & 0x80000000u) ? ~u : (u | 0x80000000u);
}
__device__ __forceinline__ float unmapf(unsigned u) {
    return __uint_as_float((u & 0x80000000u) ? (u & 0x7FFFFFFFu) : ~u);
}

// ---------- FPS v2: one block per cloud, 1024 threads, LDS-resident transposed positions ----------
// Per step: fused (update mind + local argmax) in registers -> wave shuffle reduce ->
// wave-0 parallel reduce over 16 partials -> broadcast snext via LDS -> broadcast coord read.
// Exact np semantics preserved: __fsub_rn/__fmul_rn/__fadd_rn sequential chain, strict-> keeps
// first-occurrence argmax (tie-break on global index).

template <int NP, int P>
__global__ __launch_bounds__(1024) void fps_kernel(const float* __restrict__ pos,
                                                   float* __restrict__ posq, int ns) {
    int b = blockIdx.x, t = threadIdx.x;
    const float* p = pos + (size_t)b * NP * 6;
    __shared__ float spos[6 * NP];      // transposed: spos[d*NP + j]
    __shared__ float swv[16];
    __shared__ int swi[16];
    __shared__ int snext;

    // stage transposed into LDS (coalesced global reads)
    for (int e = t; e < NP * 6; e += 1024) {
        float v = p[e];
        spos[(e % 6) * NP + (e / 6)] = v;
    }
    __syncthreads();

    // this thread's point coords into registers (conflict-free LDS reads)
    float px[P][6];
#pragma unroll
    for (int i = 0; i < P; ++i)
#pragma unroll
        for (int d = 0; d < 6; ++d)
            px[i][d] = spos[d * NP + t + 1024 * i];

    // first sample = point 0
    float c0[6];
#pragma unroll
    for (int d = 0; d < 6; ++d) c0[d] = spos[d * NP];  // broadcast read
    if (t < 6) posq[(size_t)b * ns * 6 + t] = c0[t];

    float mind[P];
    float bv = -1.f;
    int bi = 0x7fffffff;
#pragma unroll
    for (int i = 0; i < P; ++i) {
        float s = 0.f;
#pragma unroll
        for (int d = 0; d < 6; ++d) {
            float df = __fsub_rn(px[i][d], c0[d]);
            s = __fadd_rn(s, __fmul_rn(df, df));
        }
        mind[i] = s;
        if (s > bv) { bv = s; bi = t + 1024 * i; }  // ascending j: strict > keeps lowest index
    }

    for (int s = 1; s < ns; ++s) {
        // wave-level argmax reduce (64 lanes)
        float v = bv;
        int idx = bi;
#pragma unroll
        for (int off = 32; off > 0; off >>= 1) {
            float ov = __shfl_down(v, off, 64);
            int oi = __shfl_down(idx, off, 64);
            if (ov > v || (ov == v && oi < idx)) { v = ov; idx = oi; }
        }
        if ((t & 63) == 0) { swv[t >> 6] = v; swi[t >> 6] = idx; }
        __syncthreads();
        if (t < 64) {  // wave 0: parallel reduce over 16 partials
            float v2 = (t < 16) ? swv[t] : -2.f;
            int i2 = (t < 16) ? swi[t] : 0x7fffffff;
#pragma unroll
            for (int off = 8; off > 0; off >>= 1) {
                float ov = __shfl_down(v2, off, 64);
                int oi = __shfl_down(i2, off, 64);
                if (ov > v2 || (ov == v2 && oi < i2)) { v2 = ov; i2 = oi; }
            }
            if (t == 0) snext = i2;
        }
        __syncthreads();
        int nx = snext;
        float cx[6];
#pragma unroll
        for (int d = 0; d < 6; ++d) cx[d] = spos[d * NP + nx];  // broadcast read
        if (t < 6) posq[((size_t)b * ns + s) * 6 + t] = cx[t];

        // fused update + local argmax for next step
        bv = -1.f;
        bi = 0x7fffffff;
#pragma unroll
        for (int i = 0; i < P; ++i) {
            float d2 = 0.f;
#pragma unroll
            for (int d = 0; d < 6; ++d) {
                float df = __fsub_rn(px[i][d], cx[d]);
                d2 = __fadd_rn(d2, __fmul_rn(df, df));
            }
            float m = fminf(mind[i], d2);
            mind[i] = m;
            if (m > bv) { bv = m; bi = t + 1024 * i; }
        }
    }
}

// ---------- ball query: one thread per query, block=64 ----------
// keeps K smallest d2 within r2, stable ties (lower source index first) -> matches lax.top_k set

__global__ __launch_bounds__(64) void ball_kernel(const float* __restrict__ pos, const float* __restrict__ posq,
                                                  int* __restrict__ nbr, int* __restrict__ cnt,
                                                  int N, int nq, float r2) {
    __shared__ float sd[64 * K_];
    __shared__ int si[64 * K_];
    int qid = blockIdx.x * 64 + threadIdx.x;
    int b = qid / nq;
    int base = threadIdx.x * K_;
    const float* p = pos + (size_t)b * N * 6;
    float q[6];
#pragma unroll
    for (int d = 0; d < 6; ++d) q[d] = posq[(size_t)qid * 6 + d];

    int n = 0;
    for (int j = 0; j < N; ++j) {
        float d2 = dist2_rn(p + (size_t)j * 6, q);
        if (d2 <= r2) {
            if (n < K_) {
                int i = n++;
                while (i > 0 && sd[base + i - 1] > d2) {
                    sd[base + i] = sd[base + i - 1];
                    si[base + i] = si[base + i - 1];
                    --i;
                }
                sd[base + i] = d2;
                si[base + i] = j;
            } else if (d2 < sd[base + K_ - 1]) {
                int i = K_ - 1;
                while (i > 0 && sd[base + i - 1] > d2) {
                    sd[base + i] = sd[base + i - 1];
                    si[base + i] = si[base + i - 1];
                    --i;
                }
                sd[base + i] = d2;
                si[base + i] = j;
            }
        }
    }
    cnt[qid] = n;
    for (int i = 0; i < n; ++i) nbr[(size_t)qid * K_ + i] = si[base + i];
}

// ---------- SA1 conv: one wave per query; MLP 6->64->64->128, max over valid neighbors ----------

__global__ __launch_bounds__(256) void sa1_conv(const float* __restrict__ pos, const float* __restrict__ posq,
                                                const int* __restrict__ nbr, const int* __restrict__ cnt,
                                                const float* __restrict__ W1, const float* __restrict__ B1,
                                                const float* __restrict__ W2, const float* __restrict__ B2,
                                                const float* __restrict__ W3, const float* __restrict__ B3,
                                                float* __restrict__ out, int N, int nq) {
    int lane = threadIdx.x & 63;
    int w = threadIdx.x >> 6;
    int qid = blockIdx.x * 4 + w;
    int b = qid / nq;
    const float* p = pos + (size_t)b * N * 6;
    float q[6];
#pragma unroll
    for (int d = 0; d < 6; ++d) q[d] = posq[(size_t)qid * 6 + d];
    int c = cnt[qid];
    float m0 = -INFINITY, m1 = -INFINITY;

    for (int n = 0; n < c; ++n) {
        int j = nbr[(size_t)qid * K_ + n];
        float rel[6];
#pragma unroll
        for (int d = 0; d < 6; ++d) rel[d] = p[(size_t)j * 6 + d] - q[d];
        // L1: 6 -> 64 (lane = out channel)
        float a = B1[lane];
#pragma unroll
        for (int d = 0; d < 6; ++d) a = fmaf(W1[d * 64 + lane], rel[d], a);
        float h1 = fmaxf(a, 0.f);
        // L2: 64 -> 64
        float a2 = B2[lane];
        for (int k = 0; k < 64; ++k) {
            float v = __shfl(h1, k, 64);
            a2 = fmaf(W2[k * 64 + lane], v, a2);
        }
        float h2 = fmaxf(a2, 0.f);
        // L3: 64 -> 128 (lane, lane+64)
        float o0 = B3[lane], o1 = B3[64 + lane];
        for (int k = 0; k < 64; ++k) {
            float v = __shfl(h2, k, 64);
            o0 = fmaf(W3[k * 128 + lane], v, o0);
            o1 = fmaf(W3[k * 128 + 64 + lane], v, o1);
        }
        m0 = fmaxf(m0, o0);
        m1 = fmaxf(m1, o1);
    }
    out[(size_t)qid * 128 + lane] = m0;
    out[(size_t)qid * 128 + 64 + lane] = m1;
}

// ---------- SA2 conv: one wave per query; feat=[x1(128), rel(6)] -> 128 -> 128 -> 256 ----------

__global__ __launch_bounds__(256) void sa2_conv(const float* __restrict__ pos1, const float* __restrict__ posq,
                                                const int* __restrict__ nbr, const int* __restrict__ cnt,
                                                const float* __restrict__ x1,
                                                const float* __restrict__ W1, const float* __restrict__ B1,
                                                const float* __restrict__ W2, const float* __restrict__ B2,
                                                const float* __restrict__ W3, const float* __restrict__ B3,
                                                float* __restrict__ out) {
    int lane = threadIdx.x & 63;
    int w = threadIdx.x >> 6;
    int qid = blockIdx.x * 4 + w;
    int b = qid / NS2_;
    float q[6];
#pragma unroll
    for (int d = 0; d < 6; ++d) q[d] = posq[(size_t)qid * 6 + d];
    int c = cnt[qid];
    float m0 = -INFINITY, m1 = -INFINITY, m2 = -INFINITY, m3 = -INFINITY;

    for (int n = 0; n < c; ++n) {
        int j = nbr[(size_t)qid * K_ + n];
        size_t row = (size_t)b * NS1_ + j;
        const float* xs = x1 + row * 128;
        float rel[6];
#pragma unroll
        for (int d = 0; d < 6; ++d) rel[d] = pos1[row * 6 + d] - q[d];
        // L1: 134 -> 128 (lane, lane+64)
        float a0 = B1[lane], a1 = B1[64 + lane];
        for (int k = 0; k < 128; ++k) {
            float v = xs[k];
            a0 = fmaf(W1[k * 128 + lane], v, a0);
            a1 = fmaf(W1[k * 128 + 64 + lane], v, a1);
        }
#pragma unroll
        for (int d = 0; d < 6; ++d) {
            float v = rel[d];
            a0 = fmaf(W1[(128 + d) * 128 + lane], v, a0);
            a1 = fmaf(W1[(128 + d) * 128 + 64 + lane], v, a1);
        }
        float h1a = fmaxf(a0, 0.f), h1b = fmaxf(a1, 0.f);
        // L2: 128 -> 128
        float c0 = B2[lane], c1 = B2[64 + lane];
        for (int k = 0; k < 64; ++k) {
            float v = __shfl(h1a, k, 64);
            c0 = fmaf(W2[k * 128 + lane], v, c0);
            c1 = fmaf(W2[k * 128 + 64 + lane], v, c1);
        }
        for (int k = 0; k < 64; ++k) {
            float v = __shfl(h1b, k, 64);
            c0 = fmaf(W2[(64 + k) * 128 + lane], v, c0);
            c1 = fmaf(W2[(64 + k) * 128 + 64 + lane], v, c1);
        }
        float h2a = fmaxf(c0, 0.f), h2b = fmaxf(c1, 0.f);
        // L3: 128 -> 256 (lane + 64u)
        float e0 = B3[lane], e1 = B3[64 + lane], e2 = B3[128 + lane], e3 = B3[192 + lane];
        for (int k = 0; k < 64; ++k) {
            float v = __shfl(h2a, k, 64);
            e0 = fmaf(W3[k * 256 + lane], v, e0);
            e1 = fmaf(W3[k * 256 + 64 + lane], v, e1);
            e2 = fmaf(W3[k * 256 + 128 + lane], v, e2);
            e3 = fmaf(W3[k * 256 + 192 + lane], v, e3);
        }
        for (int k = 0; k < 64; ++k) {
            float v = __shfl(h2b, k, 64);
            e0 = fmaf(W3[(64 + k) * 256 + lane], v, e0);
            e1 = fmaf(W3[(64 + k) * 256 + 64 + lane], v, e1);
            e2 = fmaf(W3[(64 + k) * 256 + 128 + lane], v, e2);
            e3 = fmaf(W3[(64 + k) * 256 + 192 + lane], v, e3);
        }
        m0 = fmaxf(m0, e0);
        m1 = fmaxf(m1, e1);
        m2 = fmaxf(m2, e2);
        m3 = fmaxf(m3, e3);
    }
    out[(size_t)qid * 256 + lane] = m0;
    out[(size_t)qid * 256 + 64 + lane] = m1;
    out[(size_t)qid * 256 + 128 + lane] = m2;
    out[(size_t)qid * 256 + 192 + lane] = m3;
}

// ---------- init g ----------

__global__ void init_g(unsigned* __restrict__ g) {
    g[blockIdx.x * 1024 + threadIdx.x] = 0u;
}

// ---------- MLP3 + global max: grid (8,16), block 256; wave handles 8 queries ----------

__global__ __launch_bounds__(256) void mlp3_kernel(const float* __restrict__ x2, const float* __restrict__ pos2,
                                                   const float* __restrict__ W0, const float* __restrict__ B0,
                                                   const float* __restrict__ W1, const float* __restrict__ B1,
                                                   const float* __restrict__ W2, const float* __restrict__ B2,
                                                   unsigned* __restrict__ g) {
    int lane = threadIdx.x & 63;
    int w = threadIdx.x >> 6;
    int b = blockIdx.x;
    int qbase = blockIdx.y * 32 + w * 8;
    __shared__ float sm[4][1024];

    float me[16];
#pragma unroll
    for (int u = 0; u < 16; ++u) me[u] = -INFINITY;

    for (int qi = 0; qi < 8; ++qi) {
        int qid = b * NS2_ + qbase + qi;
        const float* xin = x2 + (size_t)qid * 256;
        // L1: 262 -> 256, 4 per lane
        float a_[4];
#pragma unroll
        for (int u = 0; u < 4; ++u) a_[u] = B0[lane + 64 * u];
        for (int k = 0; k < 256; ++k) {
            float v = xin[k];
#pragma unroll
            for (int u = 0; u < 4; ++u) a_[u] = fmaf(W0[k * 256 + lane + 64 * u], v, a_[u]);
        }
#pragma unroll
        for (int d = 0; d < 6; ++d) {
            float v = pos2[(size_t)qid * 6 + d];
#pragma unroll
            for (int u = 0; u < 4; ++u) a_[u] = fmaf(W0[(256 + d) * 256 + lane + 64 * u], v, a_[u]);
        }
        float h1_[4];
#pragma unroll
        for (int u = 0; u < 4; ++u) h1_[u] = fmaxf(a_[u], 0.f);
        // L2: 256 -> 512, 8 per lane
        float c_[8];
#pragma unroll
        for (int u = 0; u < 8; ++u) c_[u] = B1[lane + 64 * u];
#pragma unroll
        for (int ch = 0; ch < 4; ++ch) {
            float hv = h1_[ch];
            for (int k2 = 0; k2 < 64; ++k2) {
                float v = __shfl(hv, k2, 64);
                int k = ch * 64 + k2;
#pragma unroll
                for (int u = 0; u < 8; ++u) c_[u] = fmaf(W1[(size_t)k * 512 + lane + 64 * u], v, c_[u]);
            }
        }
        float h2_[8];
#pragma unroll
        for (int u = 0; u < 8; ++u) h2_[u] = fmaxf(c_[u], 0.f);
        // L3: 512 -> 1024, 16 per lane
        float e_[16];
#pragma unroll
        for (int u = 0; u < 16; ++u) e_[u] = B2[lane + 64 * u];
#pragma unroll
        for (int ch = 0; ch < 8; ++ch) {
            float hv = h2_[ch];
            for (int k2 = 0; k2 < 64; ++k2) {
                float v = __shfl(hv, k2, 64);
                int k = ch * 64 + k2;
#pragma unroll
                for (int u = 0; u < 16; ++u) e_[u] = fmaf(W2[(size_t)k * 1024 + lane + 64 * u], v, e_[u]);
            }
        }
#pragma unroll
        for (int u = 0; u < 16; ++u) me[u] = fmaxf(me[u], e_[u]);
    }

#pragma unroll
    for (int u = 0; u < 16; ++u) sm[w][lane + 64 * u] = me[u];
    __syncthreads();
    if (w == 0) {
#pragma unroll
        for (int u = 0; u < 16; ++u) {
            int ch = lane + 64 * u;
            float v = fmaxf(fmaxf(sm[0][ch], sm[1][ch]), fmaxf(sm[2][ch], sm[3][ch]));
            atomicMax(&g[b * 1024 + ch], mapf(v));
        }
    }
}

// ---------- MLP4: 1024 -> 512 (relu) -> 512; one block per b ----------

__global__ __launch_bounds__(512) void mlp4_kernel(const unsigned* __restrict__ g,
                                                   const float* __restrict__ W0, const float* __restrict__ B0,
                                                   const float* __restrict__ W1, const float* __restrict__ B1,
                                                   float* __restrict__ out) {
    int b = blockIdx.x;
    int c = threadIdx.x;
    __shared__ float h[512];
    float a = B0[c];
    for (int k = 0; k < 1024; ++k) {
        float v = unmapf(g[b * 1024 + k]);
        a = fmaf(v, W0[k * 512 + c], a);
    }
    h[c] = fmaxf(a, 0.f);
    __syncthreads();
    float o = B1[c];
    for (int k = 0; k < 512; ++k) o = fmaf(h[k], W1[k * 512 + c], o);
    out[(size_t)b * 512 + c] = o;
}

// ---------- launch ----------

extern "C" void kernel_launch(void* const* d_in, const int* in_sizes, int n_in,
                              void* d_out, int out_size, void* d_ws, size_t ws_size,
                              hipStream_t stream) {
    const float* pos = (const float*)d_in[0];  // [B*N, 6]
    const float* w1_0 = (const float*)d_in[3];
    const float* b1_0 = (const float*)d_in[4];
    const float* w1_1 = (const float*)d_in[5];
    const float* b1_1 = (const float*)d_in[6];
    const float* w1_2 = (const float*)d_in[7];
    const float* b1_2 = (const float*)d_in[8];
    const float* w2_0 = (const float*)d_in[9];
    const float* b2_0 = (const float*)d_in[10];
    const float* w2_1 = (const float*)d_in[11];
    const float* b2_1 = (const float*)d_in[12];
    const float* w2_2 = (const float*)d_in[13];
    const float* b2_2 = (const float*)d_in[14];
    const float* w3_0 = (const float*)d_in[15];
    const float* b3_0 = (const float*)d_in[16];
    const float* w3_1 = (const float*)d_in[17];
    const float* b3_1 = (const float*)d_in[18];
    const float* w3_2 = (const float*)d_in[19];
    const float* b3_2 = (const float*)d_in[20];
    const float* w4_0 = (const float*)d_in[21];
    const float* b4_0 = (const float*)d_in[22];
    const float* w4_1 = (const float*)d_in[23];
    const float* b4_1 = (const float*)d_in[24];
    float* out = (float*)d_out;

    char* ws = (char*)d_ws;
    size_t off = 0;
    float* pos1 = (float*)(ws + off);  off += (size_t)B_ * NS1_ * 6 * 4;        // 384 KB
    int* nbr1 = (int*)(ws + off);      off += (size_t)B_ * NS1_ * K_ * 4;       // 4 MB
    int* cnt1 = (int*)(ws + off);      off += (size_t)B_ * NS1_ * 4;            // 64 KB
    float* x1 = (float*)(ws + off);    off += (size_t)B_ * NS1_ * 128 * 4;      // 8 MB
    float* pos2 = (float*)(ws + off);  off += (size_t)B_ * NS2_ * 6 * 4;
    int* nbr2 = (int*)(ws + off);      off += (size_t)B_ * NS2_ * K_ * 4;       // 1 MB
    int* cnt2 = (int*)(ws + off);      off += (size_t)B_ * NS2_ * 4;
    float* x2 = (float*)(ws + off);    off += (size_t)B_ * NS2_ * 256 * 4;      // 4 MB
    unsigned* g = (unsigned*)(ws + off); off += (size_t)B_ * 1024 * 4;

    const float r2_1 = (float)(0.2 * 0.2);
    const float r2_2 = (float)(0.4 * 0.4);

    // SA1
    fps_kernel<N_, 4><<<B_, 1024, 0, stream>>>(pos, pos1, NS1_);
    ball_kernel<<<(B_ * NS1_) / 64, 64, 0, stream>>>(pos, pos1, nbr1, cnt1, N_, NS1_, r2_1);
    sa1_conv<<<(B_ * NS1_) / 4, 256, 0, stream>>>(pos, pos1, nbr1, cnt1,
                                                  w1_0, b1_0, w1_1, b1_1, w1_2, b1_2, x1, N_, NS1_);
    // SA2
    fps_kernel<NS1_, 2><<<B_, 1024, 0, stream>>>(pos1, pos2, NS2_);
    ball_kernel<<<(B_ * NS2_) / 64, 64, 0, stream>>>(pos1, pos2, nbr2, cnt2, NS1_, NS2_, r2_2);
    sa2_conv<<<(B_ * NS2_) / 4, 256, 0, stream>>>(pos1, pos2, nbr2, cnt2, x1,
                                                  w2_0, b2_0, w2_1, b2_1, w2_2, b2_2, x2);
    // MLP3 + global max
    init_g<<<B_, 1024, 0, stream>>>(g);
    mlp3_kernel<<<dim3(B_, 16), 256, 0, stream>>>(x2, pos2, w3_0, b3_0, w3_1, b3_1, w3_2, b3_2, g);
    // MLP4
    mlp4_kernel<<<B_, 512, 0, stream>>>(g, w4_0, b4_0, w4_1, b4_1, out);
}

// Round 3
// 5320.295 us; speedup vs baseline: 1.7254x; 1.3134x over previous
//
#include <hip/hip_runtime.h>
#include <math.h>

#define B_ 8
#define N_ 4096
#define D_ 6
#define K_ 64
#define NS1_ 2048
#define NS2_ 512

// ---------- helpers ----------

__device__ __forceinline__ float dist2_rn(const float* __restrict__ a, const float* __restrict__ q) {
    // exact np semantics: sequential sum of (a-b)^2, round-to-nearest each op, no fma
    float s = 0.f;
#pragma unroll
    for (int d = 0; d < 6; ++d) {
        float diff = __fsub_rn(a[d], q[d]);
        s = __fadd_rn(s, __fmul_rn(diff, diff));
    }
    return s;
}

__device__ __forceinline__ unsigned mapf(float x) {
    unsigned u = __float_as_uint(x);
    return (u & 0x80000000u) ? ~u : (u | 0x80000000u);
}
__device__ __forceinline__ float unmapf(unsigned u) {
    return __uint_as_float((u & 0x80000000u) ? (u & 0x7FFFFFFFu) : ~u);
}

// ---------- FPS v3: one block per cloud, 1024 threads, ONE barrier per step ----------
// Double-buffered partials; every wave redundantly reduces the 16 partials (no 2nd barrier,
// no serial scan); selected index parked in LDS; posq written once at the end (no per-step
// global store drain). Exact np semantics: __fsub_rn/__fmul_rn/__fadd_rn chain, fminf,
// strict-> first-occurrence argmax with lowest-index tie-break.

template <int NP, int NS, int P>
__global__ __launch_bounds__(1024) void fps_kernel(const float* __restrict__ pos,
                                                   float* __restrict__ posq) {
    const int NT = 1024, NW = 16;
    int b = blockIdx.x, t = threadIdx.x;
    int lane = t & 63, w = t >> 6;
    const float* p = pos + (size_t)b * NP * 6;
    __shared__ float spos[6 * NP];   // transposed: spos[d*NP + j]
    __shared__ int sidx[NS];
    __shared__ float swv[2][NW];
    __shared__ int swi[2][NW];

    // stage transposed into LDS (coalesced global reads)
    for (int e = t; e < NP * 6; e += NT) {
        float v = p[e];
        spos[(e % 6) * NP + (e / 6)] = v;
    }
    if (t == 0) sidx[0] = 0;
    __syncthreads();

    // this thread's point coords into registers
    float px[P][6];
#pragma unroll
    for (int i = 0; i < P; ++i)
#pragma unroll
        for (int d = 0; d < 6; ++d)
            px[i][d] = spos[d * NP + t + NT * i];

    // first sample = point 0
    float c0[6];
#pragma unroll
    for (int d = 0; d < 6; ++d) c0[d] = spos[d * NP];  // broadcast read

    float mind[P];
    float bv = -1.f;
    int bi = 0x7fffffff;
#pragma unroll
    for (int i = 0; i < P; ++i) {
        float s = 0.f;
#pragma unroll
        for (int d = 0; d < 6; ++d) {
            float df = __fsub_rn(px[i][d], c0[d]);
            s = __fadd_rn(s, __fmul_rn(df, df));
        }
        mind[i] = s;
        if (s > bv) { bv = s; bi = t + NT * i; }  // ascending j: strict > keeps lowest index
    }

    for (int s = 1; s < NS; ++s) {
        // wave-level argmax reduce (64 lanes)
        float v = bv;
        int idx = bi;
#pragma unroll
        for (int off = 32; off > 0; off >>= 1) {
            float ov = __shfl_down(v, off, 64);
            int oi = __shfl_down(idx, off, 64);
            if (ov > v || (ov == v && oi < idx)) { v = ov; idx = oi; }
        }
        if (lane == 0) { swv[s & 1][w] = v; swi[s & 1][w] = idx; }
        __syncthreads();
        // every wave redundantly reduces the 16 partials (same result everywhere)
        float v2 = (lane < NW) ? swv[s & 1][lane] : -2.f;
        int i2 = (lane < NW) ? swi[s & 1][lane] : 0x7fffffff;
#pragma unroll
        for (int off = 8; off > 0; off >>= 1) {
            float ov = __shfl_down(v2, off, 64);
            int oi = __shfl_down(i2, off, 64);
            if (ov > v2 || (ov == v2 && oi < i2)) { v2 = ov; i2 = oi; }
        }
        int nx = __shfl(i2, 0, 64);
        if (t == 0) sidx[s] = nx;  // off critical path; consumed only at the end

        float cx[6];
#pragma unroll
        for (int d = 0; d < 6; ++d) cx[d] = spos[d * NP + nx];  // broadcast read

        // fused update + local argmax for next step
        bv = -1.f;
        bi = 0x7fffffff;
#pragma unroll
        for (int i = 0; i < P; ++i) {
            float d2 = 0.f;
#pragma unroll
            for (int d = 0; d < 6; ++d) {
                float df = __fsub_rn(px[i][d], cx[d]);
                d2 = __fadd_rn(d2, __fmul_rn(df, df));
            }
            float m = fminf(mind[i], d2);
            mind[i] = m;
            if (m > bv) { bv = m; bi = t + NT * i; }
        }
    }
    __syncthreads();
    // write posq once, from LDS
    for (int s = t; s < NS; s += NT) {
        int nx = sidx[s];
#pragma unroll
        for (int d = 0; d < 6; ++d) posq[((size_t)b * NS + s) * 6 + d] = spos[d * NP + nx];
    }
}

// ---------- ball query: one thread per query, block=64 ----------

__global__ __launch_bounds__(64) void ball_kernel(const float* __restrict__ pos, const float* __restrict__ posq,
                                                  int* __restrict__ nbr, int* __restrict__ cnt,
                                                  int N, int nq, float r2) {
    __shared__ float sd[64 * K_];
    __shared__ int si[64 * K_];
    int qid = blockIdx.x * 64 + threadIdx.x;
    int b = qid / nq;
    int base = threadIdx.x * K_;
    const float* p = pos + (size_t)b * N * 6;
    float q[6];
#pragma unroll
    for (int d = 0; d < 6; ++d) q[d] = posq[(size_t)qid * 6 + d];

    int n = 0;
    for (int j = 0; j < N; ++j) {
        float d2 = dist2_rn(p + (size_t)j * 6, q);
        if (d2 <= r2) {
            if (n < K_) {
                int i = n++;
                while (i > 0 && sd[base + i - 1] > d2) {
                    sd[base + i] = sd[base + i - 1];
                    si[base + i] = si[base + i - 1];
                    --i;
                }
                sd[base + i] = d2;
                si[base + i] = j;
            } else if (d2 < sd[base + K_ - 1]) {
                int i = K_ - 1;
                while (i > 0 && sd[base + i - 1] > d2) {
                    sd[base + i] = sd[base + i - 1];
                    si[base + i] = si[base + i - 1];
                    --i;
                }
                sd[base + i] = d2;
                si[base + i] = j;
            }
        }
    }
    cnt[qid] = n;
    for (int i = 0; i < n; ++i) nbr[(size_t)qid * K_ + i] = si[base + i];
}

// ---------- SA1 conv: one wave per query; MLP 6->64->64->128, max over valid neighbors ----------

__global__ __launch_bounds__(256) void sa1_conv(const float* __restrict__ pos, const float* __restrict__ posq,
                                                const int* __restrict__ nbr, const int* __restrict__ cnt,
                                                const float* __restrict__ W1, const float* __restrict__ B1,
                                                const float* __restrict__ W2, const float* __restrict__ B2,
                                                const float* __restrict__ W3, const float* __restrict__ B3,
                                                float* __restrict__ out, int N, int nq) {
    int lane = threadIdx.x & 63;
    int w = threadIdx.x >> 6;
    int qid = blockIdx.x * 4 + w;
    int b = qid / nq;
    const float* p = pos + (size_t)b * N * 6;
    float q[6];
#pragma unroll
    for (int d = 0; d < 6; ++d) q[d] = posq[(size_t)qid * 6 + d];
    int c = cnt[qid];
    float m0 = -INFINITY, m1 = -INFINITY;

    for (int n = 0; n < c; ++n) {
        int j = nbr[(size_t)qid * K_ + n];
        float rel[6];
#pragma unroll
        for (int d = 0; d < 6; ++d) rel[d] = p[(size_t)j * 6 + d] - q[d];
        float a = B1[lane];
#pragma unroll
        for (int d = 0; d < 6; ++d) a = fmaf(W1[d * 64 + lane], rel[d], a);
        float h1 = fmaxf(a, 0.f);
        float a2 = B2[lane];
        for (int k = 0; k < 64; ++k) {
            float v = __shfl(h1, k, 64);
            a2 = fmaf(W2[k * 64 + lane], v, a2);
        }
        float h2 = fmaxf(a2, 0.f);
        float o0 = B3[lane], o1 = B3[64 + lane];
        for (int k = 0; k < 64; ++k) {
            float v = __shfl(h2, k, 64);
            o0 = fmaf(W3[k * 128 + lane], v, o0);
            o1 = fmaf(W3[k * 128 + 64 + lane], v, o1);
        }
        m0 = fmaxf(m0, o0);
        m1 = fmaxf(m1, o1);
    }
    out[(size_t)qid * 128 + lane] = m0;
    out[(size_t)qid * 128 + 64 + lane] = m1;
}

// ---------- SA2 conv: one wave per query; feat=[x1(128), rel(6)] -> 128 -> 128 -> 256 ----------

__global__ __launch_bounds__(256) void sa2_conv(const float* __restrict__ pos1, const float* __restrict__ posq,
                                                const int* __restrict__ nbr, const int* __restrict__ cnt,
                                                const float* __restrict__ x1,
                                                const float* __restrict__ W1, const float* __restrict__ B1,
                                                const float* __restrict__ W2, const float* __restrict__ B2,
                                                const float* __restrict__ W3, const float* __restrict__ B3,
                                                float* __restrict__ out) {
    int lane = threadIdx.x & 63;
    int w = threadIdx.x >> 6;
    int qid = blockIdx.x * 4 + w;
    int b = qid / NS2_;
    float q[6];
#pragma unroll
    for (int d = 0; d < 6; ++d) q[d] = posq[(size_t)qid * 6 + d];
    int c = cnt[qid];
    float m0 = -INFINITY, m1 = -INFINITY, m2 = -INFINITY, m3 = -INFINITY;

    for (int n = 0; n < c; ++n) {
        int j = nbr[(size_t)qid * K_ + n];
        size_t row = (size_t)b * NS1_ + j;
        const float* xs = x1 + row * 128;
        float rel[6];
#pragma unroll
        for (int d = 0; d < 6; ++d) rel[d] = pos1[row * 6 + d] - q[d];
        float a0 = B1[lane], a1 = B1[64 + lane];
        for (int k = 0; k < 128; ++k) {
            float v = xs[k];
            a0 = fmaf(W1[k * 128 + lane], v, a0);
            a1 = fmaf(W1[k * 128 + 64 + lane], v, a1);
        }
#pragma unroll
        for (int d = 0; d < 6; ++d) {
            float v = rel[d];
            a0 = fmaf(W1[(128 + d) * 128 + lane], v, a0);
            a1 = fmaf(W1[(128 + d) * 128 + 64 + lane], v, a1);
        }
        float h1a = fmaxf(a0, 0.f), h1b = fmaxf(a1, 0.f);
        float c0 = B2[lane], c1 = B2[64 + lane];
        for (int k = 0; k < 64; ++k) {
            float v = __shfl(h1a, k, 64);
            c0 = fmaf(W2[k * 128 + lane], v, c0);
            c1 = fmaf(W2[k * 128 + 64 + lane], v, c1);
        }
        for (int k = 0; k < 64; ++k) {
            float v = __shfl(h1b, k, 64);
            c0 = fmaf(W2[(64 + k) * 128 + lane], v, c0);
            c1 = fmaf(W2[(64 + k) * 128 + 64 + lane], v, c1);
        }
        float h2a = fmaxf(c0, 0.f), h2b = fmaxf(c1, 0.f);
        float e0 = B3[lane], e1 = B3[64 + lane], e2 = B3[128 + lane], e3 = B3[192 + lane];
        for (int k = 0; k < 64; ++k) {
            float v = __shfl(h2a, k, 64);
            e0 = fmaf(W3[k * 256 + lane], v, e0);
            e1 = fmaf(W3[k * 256 + 64 + lane], v, e1);
            e2 = fmaf(W3[k * 256 + 128 + lane], v, e2);
            e3 = fmaf(W3[k * 256 + 192 + lane], v, e3);
        }
        for (int k = 0; k < 64; ++k) {
            float v = __shfl(h2b, k, 64);
            e0 = fmaf(W3[(64 + k) * 256 + lane], v, e0);
            e1 = fmaf(W3[(64 + k) * 256 + 64 + lane], v, e1);
            e2 = fmaf(W3[(64 + k) * 256 + 128 + lane], v, e2);
            e3 = fmaf(W3[(64 + k) * 256 + 192 + lane], v, e3);
        }
        m0 = fmaxf(m0, e0);
        m1 = fmaxf(m1, e1);
        m2 = fmaxf(m2, e2);
        m3 = fmaxf(m3, e3);
    }
    out[(size_t)qid * 256 + lane] = m0;
    out[(size_t)qid * 256 + 64 + lane] = m1;
    out[(size_t)qid * 256 + 128 + lane] = m2;
    out[(size_t)qid * 256 + 192 + lane] = m3;
}

// ---------- init g ----------

__global__ void init_g(unsigned* __restrict__ g) {
    g[blockIdx.x * 1024 + threadIdx.x] = 0u;
}

// ---------- MLP3 v2: wave = 4 queries register-blocked; weight float4 reused across queries ----------
// channels laid out lane*W+u so weight loads are dwordx4; per k: 4 loads + 4 shuffles + 16*4 FMA.

__global__ __launch_bounds__(256, 1) void mlp3_kernel(const float* __restrict__ x2, const float* __restrict__ pos2,
                                                      const float* __restrict__ W0, const float* __restrict__ B0,
                                                      const float* __restrict__ W1, const float* __restrict__ B1,
                                                      const float* __restrict__ W2, const float* __restrict__ B2,
                                                      unsigned* __restrict__ g) {
    int lane = threadIdx.x & 63;
    int w = threadIdx.x >> 6;
    int qid0 = blockIdx.x * 16 + w * 4;  // 4 queries per wave, 16 per block
    int b = qid0 >> 9;                   // 512 queries per cloud

    // preload x: xr[q][j] = x2[qid][j*64 + lane]
    float xr[4][4];
#pragma unroll
    for (int q = 0; q < 4; ++q)
#pragma unroll
        for (int j = 0; j < 4; ++j) xr[q][j] = x2[(size_t)(qid0 + q) * 256 + j * 64 + lane];

    // ---- L1: 262 -> 256, out channel = lane*4+u ----
    float a[4][4];
    {
        float4 bv = *(const float4*)&B0[lane * 4];
#pragma unroll
        for (int q = 0; q < 4; ++q) { a[q][0] = bv.x; a[q][1] = bv.y; a[q][2] = bv.z; a[q][3] = bv.w; }
    }
#pragma unroll
    for (int j = 0; j < 4; ++j) {
        for (int k2 = 0; k2 < 64; ++k2) {
            int k = j * 64 + k2;
            float4 wv = *(const float4*)&W0[(size_t)k * 256 + lane * 4];
#pragma unroll
            for (int q = 0; q < 4; ++q) {
                float v = __shfl(xr[q][j], k2, 64);
                a[q][0] = fmaf(wv.x, v, a[q][0]);
                a[q][1] = fmaf(wv.y, v, a[q][1]);
                a[q][2] = fmaf(wv.z, v, a[q][2]);
                a[q][3] = fmaf(wv.w, v, a[q][3]);
            }
        }
    }
#pragma unroll
    for (int d = 0; d < 6; ++d) {
        float4 wv = *(const float4*)&W0[(size_t)(256 + d) * 256 + lane * 4];
#pragma unroll
        for (int q = 0; q < 4; ++q) {
            float v = pos2[(size_t)(qid0 + q) * 6 + d];  // broadcast load
            a[q][0] = fmaf(wv.x, v, a[q][0]);
            a[q][1] = fmaf(wv.y, v, a[q][1]);
            a[q][2] = fmaf(wv.z, v, a[q][2]);
            a[q][3] = fmaf(wv.w, v, a[q][3]);
        }
    }
    float h1[4][4];
#pragma unroll
    for (int q = 0; q < 4; ++q)
#pragma unroll
        for (int u = 0; u < 4; ++u) h1[q][u] = fmaxf(a[q][u], 0.f);

    // ---- L2: 256 -> 512, out channel = lane*8+u; input channel k=l*4+r lives at (lane=l, reg=r) ----
    float c[4][8];
    {
        float4 b0 = *(const float4*)&B1[lane * 8];
        float4 b1 = *(const float4*)&B1[lane * 8 + 4];
#pragma unroll
        for (int q = 0; q < 4; ++q) {
            c[q][0] = b0.x; c[q][1] = b0.y; c[q][2] = b0.z; c[q][3] = b0.w;
            c[q][4] = b1.x; c[q][5] = b1.y; c[q][6] = b1.z; c[q][7] = b1.w;
        }
    }
    for (int l = 0; l < 64; ++l) {
#pragma unroll
        for (int r = 0; r < 4; ++r) {
            int k = l * 4 + r;
            float4 w0 = *(const float4*)&W1[(size_t)k * 512 + lane * 8];
            float4 w1 = *(const float4*)&W1[(size_t)k * 512 + lane * 8 + 4];
#pragma unroll
            for (int q = 0; q < 4; ++q) {
                float v = __shfl(h1[q][r], l, 64);
                c[q][0] = fmaf(w0.x, v, c[q][0]);
                c[q][1] = fmaf(w0.y, v, c[q][1]);
                c[q][2] = fmaf(w0.z, v, c[q][2]);
                c[q][3] = fmaf(w0.w, v, c[q][3]);
                c[q][4] = fmaf(w1.x, v, c[q][4]);
                c[q][5] = fmaf(w1.y, v, c[q][5]);
                c[q][6] = fmaf(w1.z, v, c[q][6]);
                c[q][7] = fmaf(w1.w, v, c[q][7]);
            }
        }
    }
    float h2[4][8];
#pragma unroll
    for (int q = 0; q < 4; ++q)
#pragma unroll
        for (int u = 0; u < 8; ++u) h2[q][u] = fmaxf(c[q][u], 0.f);

    // ---- L3: 512 -> 1024, out channel = lane*16+u; input channel k=l*8+r at (lane=l, reg=r) ----
    float e[4][16];
#pragma unroll
    for (int jj = 0; jj < 4; ++jj) {
        float4 bv = *(const float4*)&B2[lane * 16 + jj * 4];
#pragma unroll
        for (int q = 0; q < 4; ++q) {
            e[q][jj * 4 + 0] = bv.x; e[q][jj * 4 + 1] = bv.y;
            e[q][jj * 4 + 2] = bv.z; e[q][jj * 4 + 3] = bv.w;
        }
    }
    for (int l = 0; l < 64; ++l) {
#pragma unroll
        for (int r = 0; r < 8; ++r) {
            int k = l * 8 + r;
            const float* wp = &W2[(size_t)k * 1024 + lane * 16];
            float4 w0 = *(const float4*)&wp[0];
            float4 w1 = *(const float4*)&wp[4];
            float4 w2 = *(const float4*)&wp[8];
            float4 w3 = *(const float4*)&wp[12];
#pragma unroll
            for (int q = 0; q < 4; ++q) {
                float v = __shfl(h2[q][r], l, 64);
                e[q][0]  = fmaf(w0.x, v, e[q][0]);
                e[q][1]  = fmaf(w0.y, v, e[q][1]);
                e[q][2]  = fmaf(w0.z, v, e[q][2]);
                e[q][3]  = fmaf(w0.w, v, e[q][3]);
                e[q][4]  = fmaf(w1.x, v, e[q][4]);
                e[q][5]  = fmaf(w1.y, v, e[q][5]);
                e[q][6]  = fmaf(w1.z, v, e[q][6]);
                e[q][7]  = fmaf(w1.w, v, e[q][7]);
                e[q][8]  = fmaf(w2.x, v, e[q][8]);
                e[q][9]  = fmaf(w2.y, v, e[q][9]);
                e[q][10] = fmaf(w2.z, v, e[q][10]);
                e[q][11] = fmaf(w2.w, v, e[q][11]);
                e[q][12] = fmaf(w3.x, v, e[q][12]);
                e[q][13] = fmaf(w3.y, v, e[q][13]);
                e[q][14] = fmaf(w3.z, v, e[q][14]);
                e[q][15] = fmaf(w3.w, v, e[q][15]);
            }
        }
    }
    // max over the wave's 4 queries, then atomic into g
#pragma unroll
    for (int u = 0; u < 16; ++u) {
        float m = fmaxf(fmaxf(e[0][u], e[1][u]), fmaxf(e[2][u], e[3][u]));
        atomicMax(&g[b * 1024 + lane * 16 + u], mapf(m));
    }
}

// ---------- MLP4: 1024 -> 512 (relu) -> 512; one block per b ----------

__global__ __launch_bounds__(512) void mlp4_kernel(const unsigned* __restrict__ g,
                                                   const float* __restrict__ W0, const float* __restrict__ B0,
                                                   const float* __restrict__ W1, const float* __restrict__ B1,
                                                   float* __restrict__ out) {
    int b = blockIdx.x;
    int c = threadIdx.x;
    __shared__ float h[512];
    float a = B0[c];
    for (int k = 0; k < 1024; ++k) {
        float v = unmapf(g[b * 1024 + k]);
        a = fmaf(v, W0[k * 512 + c], a);
    }
    h[c] = fmaxf(a, 0.f);
    __syncthreads();
    float o = B1[c];
    for (int k = 0; k < 512; ++k) o = fmaf(h[k], W1[k * 512 + c], o);
    out[(size_t)b * 512 + c] = o;
}

// ---------- launch ----------

extern "C" void kernel_launch(void* const* d_in, const int* in_sizes, int n_in,
                              void* d_out, int out_size, void* d_ws, size_t ws_size,
                              hipStream_t stream) {
    const float* pos = (const float*)d_in[0];  // [B*N, 6]
    const float* w1_0 = (const float*)d_in[3];
    const float* b1_0 = (const float*)d_in[4];
    const float* w1_1 = (const float*)d_in[5];
    const float* b1_1 = (const float*)d_in[6];
    const float* w1_2 = (const float*)d_in[7];
    const float* b1_2 = (const float*)d_in[8];
    const float* w2_0 = (const float*)d_in[9];
    const float* b2_0 = (const float*)d_in[10];
    const float* w2_1 = (const float*)d_in[11];
    const float* b2_1 = (const float*)d_in[12];
    const float* w2_2 = (const float*)d_in[13];
    const float* b2_2 = (const float*)d_in[14];
    const float* w3_0 = (const float*)d_in[15];
    const float* b3_0 = (const float*)d_in[16];
    const float* w3_1 = (const float*)d_in[17];
    const float* b3_1 = (const float*)d_in[18];
    const float* w3_2 = (const float*)d_in[19];
    const float* b3_2 = (const float*)d_in[20];
    const float* w4_0 = (const float*)d_in[21];
    const float* b4_0 = (const float*)d_in[22];
    const float* w4_1 = (const float*)d_in[23];
    const float* b4_1 = (const float*)d_in[24];
    float* out = (float*)d_out;

    char* ws = (char*)d_ws;
    size_t off = 0;
    float* pos1 = (float*)(ws + off);  off += (size_t)B_ * NS1_ * 6 * 4;
    int* nbr1 = (int*)(ws + off);      off += (size_t)B_ * NS1_ * K_ * 4;
    int* cnt1 = (int*)(ws + off);      off += (size_t)B_ * NS1_ * 4;
    float* x1 = (float*)(ws + off);    off += (size_t)B_ * NS1_ * 128 * 4;
    float* pos2 = (float*)(ws + off);  off += (size_t)B_ * NS2_ * 6 * 4;
    int* nbr2 = (int*)(ws + off);      off += (size_t)B_ * NS2_ * K_ * 4;
    int* cnt2 = (int*)(ws + off);      off += (size_t)B_ * NS2_ * 4;
    float* x2 = (float*)(ws + off);    off += (size_t)B_ * NS2_ * 256 * 4;
    unsigned* g = (unsigned*)(ws + off); off += (size_t)B_ * 1024 * 4;

    const float r2_1 = (float)(0.2 * 0.2);
    const float r2_2 = (float)(0.4 * 0.4);

    // SA1
    fps_kernel<N_, NS1_, 4><<<B_, 1024, 0, stream>>>(pos, pos1);
    ball_kernel<<<(B_ * NS1_) / 64, 64, 0, stream>>>(pos, pos1, nbr1, cnt1, N_, NS1_, r2_1);
    sa1_conv<<<(B_ * NS1_) / 4, 256, 0, stream>>>(pos, pos1, nbr1, cnt1,
                                                  w1_0, b1_0, w1_1, b1_1, w1_2, b1_2, x1, N_, NS1_);
    // SA2
    fps_kernel<NS1_, NS2_, 2><<<B_, 1024, 0, stream>>>(pos1, pos2);
    ball_kernel<<<(B_ * NS2_) / 64, 64, 0, stream>>>(pos1, pos2, nbr2, cnt2, NS1_, NS2_, r2_2);
    sa2_conv<<<(B_ * NS2_) / 4, 256, 0, stream>>>(pos1, pos2, nbr2, cnt2, x1,
                                                  w2_0, b2_0, w2_1, b2_1, w2_2, b2_2, x2);
    // MLP3 + global max
    init_g<<<B_, 1024, 0, stream>>>(g);
    mlp3_kernel<<<(B_ * NS2_) / 16, 256, 0, stream>>>(x2, pos2, w3_0, b3_0, w3_1, b3_1, w3_2, b3_2, g);
    // MLP4
    mlp4_kernel<<<B_, 512, 0, stream>>>(g, w4_0, b4_0, w4_1, b4_1, out);
}

// Round 5
// 4523.791 us; speedup vs baseline: 2.0292x; 1.1761x over previous
//
#include <hip/hip_runtime.h>
#include <math.h>

#define B_ 8
#define N_ 4096
#define D_ 6
#define K_ 64
#define NS1_ 2048
#define NS2_ 512

// ---------- helpers ----------

__device__ __forceinline__ float dist2_rn(const float* __restrict__ a, const float* __restrict__ q) {
    // exact np semantics: sequential sum of (a-b)^2, round-to-nearest each op, no fma
    float s = 0.f;
#pragma unroll
    for (int d = 0; d < 6; ++d) {
        float diff = __fsub_rn(a[d], q[d]);
        s = __fadd_rn(s, __fmul_rn(diff, diff));
    }
    return s;
}

__device__ __forceinline__ unsigned mapf(float x) {
    unsigned u = __float_as_uint(x);
    return (u & 0x80000000u) ? ~u : (u | 0x80000000u);
}
__device__ __forceinline__ float unmapf(unsigned u) {
    return __uint_as_float((u & 0x80000000u) ? (u & 0x7FFFFFFFu) : ~u);
}

// ---------- FPS v5: one block per cloud, 256 threads (1 wave/SIMD), shfl pair-compare reduce ----------
// Structure: register-resident points, fused update+argmax, ONE barrier per step, 4 partials
// (one per wave), posq written once at the end. Exact np semantics: __fsub_rn/__fmul_rn/__fadd_rn
// sequential chain, fminf, strict-> first-occurrence argmax with lowest-index tie-break.

template <int NP, int NS>
__global__ __launch_bounds__(256, 1) void fps_kernel(const float* __restrict__ pos,
                                                     float* __restrict__ posq) {
    constexpr int NT = 256;
    constexpr int P = NP / NT;
    int b = blockIdx.x, t = threadIdx.x;
    int lane = t & 63, w = t >> 6;
    const float* p = pos + (size_t)b * NP * 6;
    __shared__ float spos[NP * 6];   // row-major [j*6+d]
    __shared__ int sidx[NS];
    __shared__ float swv[2][4];
    __shared__ int swi[2][4];

    // stage into LDS, coalesced float4
    {
        const float4* src = (const float4*)p;
        float4* dst = (float4*)spos;
        for (int e = t; e < NP * 6 / 4; e += NT) dst[e] = src[e];
    }
    if (t == 0) sidx[0] = 0;
    __syncthreads();

    // this thread's point coords into registers
    float px[P][6];
#pragma unroll
    for (int i = 0; i < P; ++i)
#pragma unroll
        for (int d = 0; d < 6; ++d)
            px[i][d] = spos[(t + NT * i) * 6 + d];

    // first sample = point 0
    float cx[6];
#pragma unroll
    for (int d = 0; d < 6; ++d) cx[d] = spos[d];

    float mind[P];
    float runv = -1.f;
    int runj = 0;
#pragma unroll
    for (int i = 0; i < P; ++i) {
        float s = 0.f;
#pragma unroll
        for (int d = 0; d < 6; ++d) {
            float df = __fsub_rn(px[i][d], cx[d]);
            s = __fadd_rn(s, __fmul_rn(df, df));
        }
        mind[i] = s;
        if (s > runv) { runv = s; runj = t + NT * i; }  // ascending global idx: strict > keeps lowest
    }

    for (int s = 1; s < NS; ++s) {
        // wave-level argmax reduce (64 lanes), known-good pair-compare idiom
        float v = runv;
        int idx = runj;
#pragma unroll
        for (int off = 32; off > 0; off >>= 1) {
            float ov = __shfl_down(v, off, 64);
            int oi = __shfl_down(idx, off, 64);
            if (ov > v || (ov == v && oi < idx)) { v = ov; idx = oi; }
        }
        if (lane == 0) { swv[s & 1][w] = v; swi[s & 1][w] = idx; }
        __syncthreads();
        // every wave redundantly reduces the 4 partials (2 shfl levels)
        float v2 = (lane < 4) ? swv[s & 1][lane] : -2.f;
        int i2 = (lane < 4) ? swi[s & 1][lane] : 0x7fffffff;
#pragma unroll
        for (int off = 2; off > 0; off >>= 1) {
            float ov = __shfl_down(v2, off, 64);
            int oi = __shfl_down(i2, off, 64);
            if (ov > v2 || (ov == v2 && oi < i2)) { v2 = ov; i2 = oi; }
        }
        int nx = __shfl(i2, 0, 64);
        if (t == 0) sidx[s] = nx;  // off critical path; consumed only at the end

        // broadcast-read new center coords (nx uniform)
        const float2* sv2 = (const float2*)spos;
        float2 ca = sv2[nx * 3], cb = sv2[nx * 3 + 1], cc = sv2[nx * 3 + 2];
        cx[0] = ca.x; cx[1] = ca.y; cx[2] = cb.x; cx[3] = cb.y; cx[4] = cc.x; cx[5] = cc.y;

        // fused update + local argmax
        runv = -1.f;
        runj = 0;
#pragma unroll
        for (int i = 0; i < P; ++i) {
            float d2 = 0.f;
#pragma unroll
            for (int d = 0; d < 6; ++d) {
                float df = __fsub_rn(px[i][d], cx[d]);
                d2 = __fadd_rn(d2, __fmul_rn(df, df));
            }
            float m = fminf(mind[i], d2);
            mind[i] = m;
            if (m > runv) { runv = m; runj = t + NT * i; }
        }
    }
    __syncthreads();
    // write posq once, from LDS
    for (int s2 = t; s2 < NS; s2 += NT) {
        int nx = sidx[s2];
#pragma unroll
        for (int d = 0; d < 6; ++d) posq[((size_t)b * NS + s2) * 6 + d] = spos[nx * 6 + d];
    }
}

// ---------- ball query: one thread per query, block=64, interleaved LDS top-K ----------
// layout sd[i*64+tid]: all lanes at slot i hit distinct banks (old tid*K+i layout was a
// 64-way conflict on every access). Same exact semantics: ascending-j insertion sort,
// equal-d2 keeps lower j first, full-list strict-less drop -> matches lax.top_k set.

__global__ __launch_bounds__(64) void ball_kernel(const float* __restrict__ pos, const float* __restrict__ posq,
                                                  int* __restrict__ nbr, int* __restrict__ cnt,
                                                  int N, int nq, float r2) {
    __shared__ float sd[K_ * 64];
    __shared__ int si[K_ * 64];
    int tid = threadIdx.x;
    int qid = blockIdx.x * 64 + tid;
    int b = qid / nq;
    const float* p = pos + (size_t)b * N * 6;
    float q[6];
#pragma unroll
    for (int d = 0; d < 6; ++d) q[d] = posq[(size_t)qid * 6 + d];

    int n = 0;
    for (int j = 0; j < N; ++j) {
        float d2 = dist2_rn(p + (size_t)j * 6, q);
        if (d2 <= r2) {
            if (n < K_) {
                int i = n++;
                while (i > 0 && sd[(i - 1) * 64 + tid] > d2) {
                    sd[i * 64 + tid] = sd[(i - 1) * 64 + tid];
                    si[i * 64 + tid] = si[(i - 1) * 64 + tid];
                    --i;
                }
                sd[i * 64 + tid] = d2;
                si[i * 64 + tid] = j;
            } else if (d2 < sd[(K_ - 1) * 64 + tid]) {
                int i = K_ - 1;
                while (i > 0 && sd[(i - 1) * 64 + tid] > d2) {
                    sd[i * 64 + tid] = sd[(i - 1) * 64 + tid];
                    si[i * 64 + tid] = si[(i - 1) * 64 + tid];
                    --i;
                }
                sd[i * 64 + tid] = d2;
                si[i * 64 + tid] = j;
            }
        }
    }
    cnt[qid] = n;
    for (int i = 0; i < n; ++i) nbr[(size_t)qid * K_ + i] = si[i * 64 + tid];
}

// ---------- SA1 conv: one wave per query; MLP 6->64->64->128, max over valid neighbors ----------

__global__ __launch_bounds__(256) void sa1_conv(const float* __restrict__ pos, const float* __restrict__ posq,
                                                const int* __restrict__ nbr, const int* __restrict__ cnt,
                                                const float* __restrict__ W1, const float* __restrict__ B1,
                                                const float* __restrict__ W2, const float* __restrict__ B2,
                                                const float* __restrict__ W3, const float* __restrict__ B3,
                                                float* __restrict__ out, int N, int nq) {
    int lane = threadIdx.x & 63;
    int w = threadIdx.x >> 6;
    int qid = blockIdx.x * 4 + w;
    int b = qid / nq;
    const float* p = pos + (size_t)b * N * 6;
    float q[6];
#pragma unroll
    for (int d = 0; d < 6; ++d) q[d] = posq[(size_t)qid * 6 + d];
    int c = cnt[qid];
    float m0 = -INFINITY, m1 = -INFINITY;

    for (int n = 0; n < c; ++n) {
        int j = nbr[(size_t)qid * K_ + n];
        float rel[6];
#pragma unroll
        for (int d = 0; d < 6; ++d) rel[d] = p[(size_t)j * 6 + d] - q[d];
        float a = B1[lane];
#pragma unroll
        for (int d = 0; d < 6; ++d) a = fmaf(W1[d * 64 + lane], rel[d], a);
        float h1 = fmaxf(a, 0.f);
        float a2 = B2[lane];
        for (int k = 0; k < 64; ++k) {
            float v = __shfl(h1, k, 64);
            a2 = fmaf(W2[k * 64 + lane], v, a2);
        }
        float h2 = fmaxf(a2, 0.f);
        float o0 = B3[lane], o1 = B3[64 + lane];
        for (int k = 0; k < 64; ++k) {
            float v = __shfl(h2, k, 64);
            o0 = fmaf(W3[k * 128 + lane], v, o0);
            o1 = fmaf(W3[k * 128 + 64 + lane], v, o1);
        }
        m0 = fmaxf(m0, o0);
        m1 = fmaxf(m1, o1);
    }
    out[(size_t)qid * 128 + lane] = m0;
    out[(size_t)qid * 128 + 64 + lane] = m1;
}

// ---------- SA2 conv: one wave per query; feat=[x1(128), rel(6)] -> 128 -> 128 -> 256 ----------

__global__ __launch_bounds__(256) void sa2_conv(const float* __restrict__ pos1, const float* __restrict__ posq,
                                                const int* __restrict__ nbr, const int* __restrict__ cnt,
                                                const float* __restrict__ x1,
                                                const float* __restrict__ W1, const float* __restrict__ B1,
                                                const float* __restrict__ W2, const float* __restrict__ B2,
                                                const float* __restrict__ W3, const float* __restrict__ B3,
                                                float* __restrict__ out) {
    int lane = threadIdx.x & 63;
    int w = threadIdx.x >> 6;
    int qid = blockIdx.x * 4 + w;
    int b = qid / NS2_;
    float q[6];
#pragma unroll
    for (int d = 0; d < 6; ++d) q[d] = posq[(size_t)qid * 6 + d];
    int c = cnt[qid];
    float m0 = -INFINITY, m1 = -INFINITY, m2 = -INFINITY, m3 = -INFINITY;

    for (int n = 0; n < c; ++n) {
        int j = nbr[(size_t)qid * K_ + n];
        size_t row = (size_t)b * NS1_ + j;
        const float* xs = x1 + row * 128;
        float rel[6];
#pragma unroll
        for (int d = 0; d < 6; ++d) rel[d] = pos1[row * 6 + d] - q[d];
        float a0 = B1[lane], a1 = B1[64 + lane];
        for (int k = 0; k < 128; ++k) {
            float v = xs[k];
            a0 = fmaf(W1[k * 128 + lane], v, a0);
            a1 = fmaf(W1[k * 128 + 64 + lane], v, a1);
        }
#pragma unroll
        for (int d = 0; d < 6; ++d) {
            float v = rel[d];
            a0 = fmaf(W1[(128 + d) * 128 + lane], v, a0);
            a1 = fmaf(W1[(128 + d) * 128 + 64 + lane], v, a1);
        }
        float h1a = fmaxf(a0, 0.f), h1b = fmaxf(a1, 0.f);
        float c0 = B2[lane], c1 = B2[64 + lane];
        for (int k = 0; k < 64; ++k) {
            float v = __shfl(h1a, k, 64);
            c0 = fmaf(W2[k * 128 + lane], v, c0);
            c1 = fmaf(W2[k * 128 + 64 + lane], v, c1);
        }
        for (int k = 0; k < 64; ++k) {
            float v = __shfl(h1b, k, 64);
            c0 = fmaf(W2[(64 + k) * 128 + lane], v, c0);
            c1 = fmaf(W2[(64 + k) * 128 + 64 + lane], v, c1);
        }
        float h2a = fmaxf(c0, 0.f), h2b = fmaxf(c1, 0.f);
        float e0 = B3[lane], e1 = B3[64 + lane], e2 = B3[128 + lane], e3 = B3[192 + lane];
        for (int k = 0; k < 64; ++k) {
            float v = __shfl(h2a, k, 64);
            e0 = fmaf(W3[k * 256 + lane], v, e0);
            e1 = fmaf(W3[k * 256 + 64 + lane], v, e1);
            e2 = fmaf(W3[k * 256 + 128 + lane], v, e2);
            e3 = fmaf(W3[k * 256 + 192 + lane], v, e3);
        }
        for (int k = 0; k < 64; ++k) {
            float v = __shfl(h2b, k, 64);
            e0 = fmaf(W3[(64 + k) * 256 + lane], v, e0);
            e1 = fmaf(W3[(64 + k) * 256 + 64 + lane], v, e1);
            e2 = fmaf(W3[(64 + k) * 256 + 128 + lane], v, e2);
            e3 = fmaf(W3[(64 + k) * 256 + 192 + lane], v, e3);
        }
        m0 = fmaxf(m0, e0);
        m1 = fmaxf(m1, e1);
        m2 = fmaxf(m2, e2);
        m3 = fmaxf(m3, e3);
    }
    out[(size_t)qid * 256 + lane] = m0;
    out[(size_t)qid * 256 + 64 + lane] = m1;
    out[(size_t)qid * 256 + 128 + lane] = m2;
    out[(size_t)qid * 256 + 192 + lane] = m3;
}

// ---------- init g ----------

__global__ void init_g(unsigned* __restrict__ g) {
    g[blockIdx.x * 1024 + threadIdx.x] = 0u;
}

// ---------- MLP3 v2: wave = 4 queries register-blocked; weight float4 reused across queries ----------

__global__ __launch_bounds__(256, 1) void mlp3_kernel(const float* __restrict__ x2, const float* __restrict__ pos2,
                                                      const float* __restrict__ W0, const float* __restrict__ B0,
                                                      const float* __restrict__ W1, const float* __restrict__ B1,
                                                      const float* __restrict__ W2, const float* __restrict__ B2,
                                                      unsigned* __restrict__ g) {
    int lane = threadIdx.x & 63;
    int w = threadIdx.x >> 6;
    int qid0 = blockIdx.x * 16 + w * 4;  // 4 queries per wave, 16 per block
    int b = qid0 >> 9;                   // 512 queries per cloud

    float xr[4][4];
#pragma unroll
    for (int q = 0; q < 4; ++q)
#pragma unroll
        for (int j = 0; j < 4; ++j) xr[q][j] = x2[(size_t)(qid0 + q) * 256 + j * 64 + lane];

    // ---- L1: 262 -> 256, out channel = lane*4+u ----
    float a[4][4];
    {
        float4 bv = *(const float4*)&B0[lane * 4];
#pragma unroll
        for (int q = 0; q < 4; ++q) { a[q][0] = bv.x; a[q][1] = bv.y; a[q][2] = bv.z; a[q][3] = bv.w; }
    }
#pragma unroll
    for (int j = 0; j < 4; ++j) {
        for (int k2 = 0; k2 < 64; ++k2) {
            int k = j * 64 + k2;
            float4 wv = *(const float4*)&W0[(size_t)k * 256 + lane * 4];
#pragma unroll
            for (int q = 0; q < 4; ++q) {
                float v = __shfl(xr[q][j], k2, 64);
                a[q][0] = fmaf(wv.x, v, a[q][0]);
                a[q][1] = fmaf(wv.y, v, a[q][1]);
                a[q][2] = fmaf(wv.z, v, a[q][2]);
                a[q][3] = fmaf(wv.w, v, a[q][3]);
            }
        }
    }
#pragma unroll
    for (int d = 0; d < 6; ++d) {
        float4 wv = *(const float4*)&W0[(size_t)(256 + d) * 256 + lane * 4];
#pragma unroll
        for (int q = 0; q < 4; ++q) {
            float v = pos2[(size_t)(qid0 + q) * 6 + d];
            a[q][0] = fmaf(wv.x, v, a[q][0]);
            a[q][1] = fmaf(wv.y, v, a[q][1]);
            a[q][2] = fmaf(wv.z, v, a[q][2]);
            a[q][3] = fmaf(wv.w, v, a[q][3]);
        }
    }
    float h1[4][4];
#pragma unroll
    for (int q = 0; q < 4; ++q)
#pragma unroll
        for (int u = 0; u < 4; ++u) h1[q][u] = fmaxf(a[q][u], 0.f);

    // ---- L2: 256 -> 512, out channel = lane*8+u ----
    float c[4][8];
    {
        float4 b0 = *(const float4*)&B1[lane * 8];
        float4 b1 = *(const float4*)&B1[lane * 8 + 4];
#pragma unroll
        for (int q = 0; q < 4; ++q) {
            c[q][0] = b0.x; c[q][1] = b0.y; c[q][2] = b0.z; c[q][3] = b0.w;
            c[q][4] = b1.x; c[q][5] = b1.y; c[q][6] = b1.z; c[q][7] = b1.w;
        }
    }
    for (int l = 0; l < 64; ++l) {
#pragma unroll
        for (int r = 0; r < 4; ++r) {
            int k = l * 4 + r;
            float4 w0 = *(const float4*)&W1[(size_t)k * 512 + lane * 8];
            float4 w1 = *(const float4*)&W1[(size_t)k * 512 + lane * 8 + 4];
#pragma unroll
            for (int q = 0; q < 4; ++q) {
                float v = __shfl(h1[q][r], l, 64);
                c[q][0] = fmaf(w0.x, v, c[q][0]);
                c[q][1] = fmaf(w0.y, v, c[q][1]);
                c[q][2] = fmaf(w0.z, v, c[q][2]);
                c[q][3] = fmaf(w0.w, v, c[q][3]);
                c[q][4] = fmaf(w1.x, v, c[q][4]);
                c[q][5] = fmaf(w1.y, v, c[q][5]);
                c[q][6] = fmaf(w1.z, v, c[q][6]);
                c[q][7] = fmaf(w1.w, v, c[q][7]);
            }
        }
    }
    float h2[4][8];
#pragma unroll
    for (int q = 0; q < 4; ++q)
#pragma unroll
        for (int u = 0; u < 8; ++u) h2[q][u] = fmaxf(c[q][u], 0.f);

    // ---- L3: 512 -> 1024, out channel = lane*16+u ----
    float e[4][16];
#pragma unroll
    for (int jj = 0; jj < 4; ++jj) {
        float4 bv = *(const float4*)&B2[lane * 16 + jj * 4];
#pragma unroll
        for (int q = 0; q < 4; ++q) {
            e[q][jj * 4 + 0] = bv.x; e[q][jj * 4 + 1] = bv.y;
            e[q][jj * 4 + 2] = bv.z; e[q][jj * 4 + 3] = bv.w;
        }
    }
    for (int l = 0; l < 64; ++l) {
#pragma unroll
        for (int r = 0; r < 8; ++r) {
            int k = l * 8 + r;
            const float* wp = &W2[(size_t)k * 1024 + lane * 16];
            float4 w0 = *(const float4*)&wp[0];
            float4 w1 = *(const float4*)&wp[4];
            float4 w2 = *(const float4*)&wp[8];
            float4 w3 = *(const float4*)&wp[12];
#pragma unroll
            for (int q = 0; q < 4; ++q) {
                float v = __shfl(h2[q][r], l, 64);
                e[q][0]  = fmaf(w0.x, v, e[q][0]);
                e[q][1]  = fmaf(w0.y, v, e[q][1]);
                e[q][2]  = fmaf(w0.z, v, e[q][2]);
                e[q][3]  = fmaf(w0.w, v, e[q][3]);
                e[q][4]  = fmaf(w1.x, v, e[q][4]);
                e[q][5]  = fmaf(w1.y, v, e[q][5]);
                e[q][6]  = fmaf(w1.z, v, e[q][6]);
                e[q][7]  = fmaf(w1.w, v, e[q][7]);
                e[q][8]  = fmaf(w2.x, v, e[q][8]);
                e[q][9]  = fmaf(w2.y, v, e[q][9]);
                e[q][10] = fmaf(w2.z, v, e[q][10]);
                e[q][11] = fmaf(w2.w, v, e[q][11]);
                e[q][12] = fmaf(w3.x, v, e[q][12]);
                e[q][13] = fmaf(w3.y, v, e[q][13]);
                e[q][14] = fmaf(w3.z, v, e[q][14]);
                e[q][15] = fmaf(w3.w, v, e[q][15]);
            }
        }
    }
#pragma unroll
    for (int u = 0; u < 16; ++u) {
        float m = fmaxf(fmaxf(e[0][u], e[1][u]), fmaxf(e[2][u], e[3][u]));
        atomicMax(&g[b * 1024 + lane * 16 + u], mapf(m));
    }
}

// ---------- MLP4: 1024 -> 512 (relu) -> 512; one block per b ----------

__global__ __launch_bounds__(512) void mlp4_kernel(const unsigned* __restrict__ g,
                                                   const float* __restrict__ W0, const float* __restrict__ B0,
                                                   const float* __restrict__ W1, const float* __restrict__ B1,
                                                   float* __restrict__ out) {
    int b = blockIdx.x;
    int c = threadIdx.x;
    __shared__ float h[512];
    float a = B0[c];
    for (int k = 0; k < 1024; ++k) {
        float v = unmapf(g[b * 1024 + k]);
        a = fmaf(v, W0[k * 512 + c], a);
    }
    h[c] = fmaxf(a, 0.f);
    __syncthreads();
    float o = B1[c];
    for (int k = 0; k < 512; ++k) o = fmaf(h[k], W1[k * 512 + c], o);
    out[(size_t)b * 512 + c] = o;
}

// ---------- launch ----------

extern "C" void kernel_launch(void* const* d_in, const int* in_sizes, int n_in,
                              void* d_out, int out_size, void* d_ws, size_t ws_size,
                              hipStream_t stream) {
    const float* pos = (const float*)d_in[0];  // [B*N, 6]
    const float* w1_0 = (const float*)d_in[3];
    const float* b1_0 = (const float*)d_in[4];
    const float* w1_1 = (const float*)d_in[5];
    const float* b1_1 = (const float*)d_in[6];
    const float* w1_2 = (const float*)d_in[7];
    const float* b1_2 = (const float*)d_in[8];
    const float* w2_0 = (const float*)d_in[9];
    const float* b2_0 = (const float*)d_in[10];
    const float* w2_1 = (const float*)d_in[11];
    const float* b2_1 = (const float*)d_in[12];
    const float* w2_2 = (const float*)d_in[13];
    const float* b2_2 = (const float*)d_in[14];
    const float* w3_0 = (const float*)d_in[15];
    const float* b3_0 = (const float*)d_in[16];
    const float* w3_1 = (const float*)d_in[17];
    const float* b3_1 = (const float*)d_in[18];
    const float* w3_2 = (const float*)d_in[19];
    const float* b3_2 = (const float*)d_in[20];
    const float* w4_0 = (const float*)d_in[21];
    const float* b4_0 = (const float*)d_in[22];
    const float* w4_1 = (const float*)d_in[23];
    const float* b4_1 = (const float*)d_in[24];
    float* out = (float*)d_out;

    char* ws = (char*)d_ws;
    size_t off = 0;
    float* pos1 = (float*)(ws + off);  off += (size_t)B_ * NS1_ * 6 * 4;
    int* nbr1 = (int*)(ws + off);      off += (size_t)B_ * NS1_ * K_ * 4;
    int* cnt1 = (int*)(ws + off);      off += (size_t)B_ * NS1_ * 4;
    float* x1 = (float*)(ws + off);    off += (size_t)B_ * NS1_ * 128 * 4;
    float* pos2 = (float*)(ws + off);  off += (size_t)B_ * NS2_ * 6 * 4;
    int* nbr2 = (int*)(ws + off);      off += (size_t)B_ * NS2_ * K_ * 4;
    int* cnt2 = (int*)(ws + off);      off += (size_t)B_ * NS2_ * 4;
    float* x2 = (float*)(ws + off);    off += (size_t)B_ * NS2_ * 256 * 4;
    unsigned* g = (unsigned*)(ws + off); off += (size_t)B_ * 1024 * 4;

    const float r2_1 = (float)(0.2 * 0.2);
    const float r2_2 = (float)(0.4 * 0.4);

    // SA1
    fps_kernel<N_, NS1_><<<B_, 256, 0, stream>>>(pos, pos1);
    ball_kernel<<<(B_ * NS1_) / 64, 64, 0, stream>>>(pos, pos1, nbr1, cnt1, N_, NS1_, r2_1);
    sa1_conv<<<(B_ * NS1_) / 4, 256, 0, stream>>>(pos, pos1, nbr1, cnt1,
                                                  w1_0, b1_0, w1_1, b1_1, w1_2, b1_2, x1, N_, NS1_);
    // SA2
    fps_kernel<NS1_, NS2_><<<B_, 256, 0, stream>>>(pos1, pos2);
    ball_kernel<<<(B_ * NS2_) / 64, 64, 0, stream>>>(pos1, pos2, nbr2, cnt2, NS1_, NS2_, r2_2);
    sa2_conv<<<(B_ * NS2_) / 4, 256, 0, stream>>>(pos1, pos2, nbr2, cnt2, x1,
                                                  w2_0, b2_0, w2_1, b2_1, w2_2, b2_2, x2);
    // MLP3 + global max
    init_g<<<B_, 1024, 0, stream>>>(g);
    mlp3_kernel<<<(B_ * NS2_) / 16, 256, 0, stream>>>(x2, pos2, w3_0, b3_0, w3_1, b3_1, w3_2, b3_2, g);
    // MLP4
    mlp4_kernel<<<B_, 512, 0, stream>>>(g, w4_0, b4_0, w4_1, b4_1, out);
}

// Round 6
// 3241.132 us; speedup vs baseline: 2.8323x; 1.3957x over previous
//
#include <hip/hip_runtime.h>
#include <math.h>

#define B_ 8
#define N_ 4096
#define D_ 6
#define K_ 64
#define NS1_ 2048
#define NS2_ 512

// ---------- helpers ----------

__device__ __forceinline__ float dist2_rn(const float* __restrict__ a, const float* __restrict__ q) {
    // exact np semantics: sequential sum of (a-b)^2, round-to-nearest each op, no fma
    float s = 0.f;
#pragma unroll
    for (int d = 0; d < 6; ++d) {
        float diff = __fsub_rn(a[d], q[d]);
        s = __fadd_rn(s, __fmul_rn(diff, diff));
    }
    return s;
}

__device__ __forceinline__ unsigned mapf(float x) {
    unsigned u = __float_as_uint(x);
    return (u & 0x80000000u) ? ~u : (u | 0x80000000u);
}
__device__ __forceinline__ float unmapf(unsigned u) {
    return __uint_as_float((u & 0x80000000u) ? (u & 0x7FFFFFFFu) : ~u);
}

__device__ __forceinline__ unsigned long long kmax64(unsigned long long a, unsigned long long b) {
    return a > b ? a : b;
}

// one DPP move on a u64 (two independent 32-bit DPPs, same ctrl); invalid lanes keep own value
template <int CTRL>
__device__ __forceinline__ unsigned long long dpp64(unsigned long long k) {
    int lo = (int)(unsigned)(k & 0xFFFFFFFFull);
    int hi = (int)(unsigned)(k >> 32);
    int nlo = __builtin_amdgcn_update_dpp(lo, lo, CTRL, 0xF, 0xF, false);
    int nhi = __builtin_amdgcn_update_dpp(hi, hi, CTRL, 0xF, 0xF, false);
    return ((unsigned long long)(unsigned)nhi << 32) | (unsigned)nlo;
}

// ---------- FPS v6: round-5 structure, DPP argmax reduce (VALU-latency, no ds_bpermute chains) ----------
// key = d2_bits<<32 | ~gidx  (d2>=0 so float bits order as unsigned; ~gidx -> lowest index on ties).
// Wave reduce: row_shr 1/2/4/8 + row_bcast15/31 -> lane 63 holds wave max (classic gfx9 ladder).
// Exact np semantics preserved: __fsub_rn/__fmul_rn/__fadd_rn chain, fminf, first-occurrence argmax.

template <int NP, int NS>
__global__ __launch_bounds__(256, 1) void fps_kernel(const float* __restrict__ pos,
                                                     float* __restrict__ posq) {
    constexpr int NT = 256;
    constexpr int P = NP / NT;
    int b = blockIdx.x, t = threadIdx.x;
    int lane = t & 63, w = t >> 6;
    const float* p = pos + (size_t)b * NP * 6;
    __shared__ float spos[NP * 6];   // row-major [j*6+d]
    __shared__ int sidx[NS];
    __shared__ unsigned long long part[2][4];

    // stage into LDS, coalesced float4
    {
        const float4* src = (const float4*)p;
        float4* dst = (float4*)spos;
        for (int e = t; e < NP * 6 / 4; e += NT) dst[e] = src[e];
    }
    if (t == 0) sidx[0] = 0;
    __syncthreads();

    // this thread's point coords into registers
    float px[P][6];
#pragma unroll
    for (int i = 0; i < P; ++i)
#pragma unroll
        for (int d = 0; d < 6; ++d)
            px[i][d] = spos[(t + NT * i) * 6 + d];

    // first sample = point 0
    float cx[6];
#pragma unroll
    for (int d = 0; d < 6; ++d) cx[d] = spos[d];

    float mind[P];
    float runv = -1.f;
    int runj = 0;
#pragma unroll
    for (int i = 0; i < P; ++i) {
        float s = 0.f;
#pragma unroll
        for (int d = 0; d < 6; ++d) {
            float df = __fsub_rn(px[i][d], cx[d]);
            s = __fadd_rn(s, __fmul_rn(df, df));
        }
        mind[i] = s;
        if (s > runv) { runv = s; runj = t + NT * i; }  // ascending global idx: strict > keeps lowest
    }

    for (int s = 1; s < NS; ++s) {
        // wave-level argmax reduce via DPP ladder on packed key
        unsigned long long key =
            ((unsigned long long)__float_as_uint(runv) << 32) | (unsigned)(~runj);
        key = kmax64(key, dpp64<0x111>(key));  // row_shr:1
        key = kmax64(key, dpp64<0x112>(key));  // row_shr:2
        key = kmax64(key, dpp64<0x114>(key));  // row_shr:4
        key = kmax64(key, dpp64<0x118>(key));  // row_shr:8  -> lane15 of each row has row max
        key = kmax64(key, dpp64<0x142>(key));  // row_bcast:15
        key = kmax64(key, dpp64<0x143>(key));  // row_bcast:31 -> lane 63 has wave max
        if (lane == 63) part[s & 1][w] = key;
        __syncthreads();
        // every wave redundantly reduces the 4 partials (2 DPP levels in row 0..3)
        unsigned long long kk = part[s & 1][lane & 3];
        kk = kmax64(kk, dpp64<0x111>(kk));
        kk = kmax64(kk, dpp64<0x112>(kk));   // lane 3 = max of partials 0..3
        int nx = ~__builtin_amdgcn_readlane((int)(unsigned)(kk & 0xFFFFFFFFull), 3);
        if (t == 0) sidx[s] = nx;  // off critical path; consumed only at the end

        // broadcast-read new center coords (nx uniform)
        const float2* sv2 = (const float2*)spos;
        float2 ca = sv2[nx * 3], cb = sv2[nx * 3 + 1], cc = sv2[nx * 3 + 2];
        cx[0] = ca.x; cx[1] = ca.y; cx[2] = cb.x; cx[3] = cb.y; cx[4] = cc.x; cx[5] = cc.y;

        // fused update + local argmax
        runv = -1.f;
        runj = 0;
#pragma unroll
        for (int i = 0; i < P; ++i) {
            float d2 = 0.f;
#pragma unroll
            for (int d = 0; d < 6; ++d) {
                float df = __fsub_rn(px[i][d], cx[d]);
                d2 = __fadd_rn(d2, __fmul_rn(df, df));
            }
            float m = fminf(mind[i], d2);
            mind[i] = m;
            if (m > runv) { runv = m; runj = t + NT * i; }
        }
    }
    __syncthreads();
    // write posq once, from LDS
    for (int s2 = t; s2 < NS; s2 += NT) {
        int nx = sidx[s2];
#pragma unroll
        for (int d = 0; d < 6; ++d) posq[((size_t)b * NS + s2) * 6 + d] = spos[nx * 6 + d];
    }
}

// ---------- ball query: one thread per query, block=64, interleaved LDS top-K ----------

__global__ __launch_bounds__(64) void ball_kernel(const float* __restrict__ pos, const float* __restrict__ posq,
                                                  int* __restrict__ nbr, int* __restrict__ cnt,
                                                  int N, int nq, float r2) {
    __shared__ float sd[K_ * 64];
    __shared__ int si[K_ * 64];
    int tid = threadIdx.x;
    int qid = blockIdx.x * 64 + tid;
    int b = qid / nq;
    const float* p = pos + (size_t)b * N * 6;
    float q[6];
#pragma unroll
    for (int d = 0; d < 6; ++d) q[d] = posq[(size_t)qid * 6 + d];

    int n = 0;
    for (int j = 0; j < N; ++j) {
        float d2 = dist2_rn(p + (size_t)j * 6, q);
        if (d2 <= r2) {
            if (n < K_) {
                int i = n++;
                while (i > 0 && sd[(i - 1) * 64 + tid] > d2) {
                    sd[i * 64 + tid] = sd[(i - 1) * 64 + tid];
                    si[i * 64 + tid] = si[(i - 1) * 64 + tid];
                    --i;
                }
                sd[i * 64 + tid] = d2;
                si[i * 64 + tid] = j;
            } else if (d2 < sd[(K_ - 1) * 64 + tid]) {
                int i = K_ - 1;
                while (i > 0 && sd[(i - 1) * 64 + tid] > d2) {
                    sd[i * 64 + tid] = sd[(i - 1) * 64 + tid];
                    si[i * 64 + tid] = si[(i - 1) * 64 + tid];
                    --i;
                }
                sd[i * 64 + tid] = d2;
                si[i * 64 + tid] = j;
            }
        }
    }
    cnt[qid] = n;
    for (int i = 0; i < n; ++i) nbr[(size_t)qid * K_ + i] = si[i * 64 + tid];
}

// ---------- SA1 conv: one wave per query; MLP 6->64->64->128, max over valid neighbors ----------

__global__ __launch_bounds__(256) void sa1_conv(const float* __restrict__ pos, const float* __restrict__ posq,
                                                const int* __restrict__ nbr, const int* __restrict__ cnt,
                                                const float* __restrict__ W1, const float* __restrict__ B1,
                                                const float* __restrict__ W2, const float* __restrict__ B2,
                                                const float* __restrict__ W3, const float* __restrict__ B3,
                                                float* __restrict__ out, int N, int nq) {
    int lane = threadIdx.x & 63;
    int w = threadIdx.x >> 6;
    int qid = blockIdx.x * 4 + w;
    int b = qid / nq;
    const float* p = pos + (size_t)b * N * 6;
    float q[6];
#pragma unroll
    for (int d = 0; d < 6; ++d) q[d] = posq[(size_t)qid * 6 + d];
    int c = cnt[qid];
    float m0 = -INFINITY, m1 = -INFINITY;

    for (int n = 0; n < c; ++n) {
        int j = nbr[(size_t)qid * K_ + n];
        float rel[6];
#pragma unroll
        for (int d = 0; d < 6; ++d) rel[d] = p[(size_t)j * 6 + d] - q[d];
        float a = B1[lane];
#pragma unroll
        for (int d = 0; d < 6; ++d) a = fmaf(W1[d * 64 + lane], rel[d], a);
        float h1 = fmaxf(a, 0.f);
        float a2 = B2[lane];
        for (int k = 0; k < 64; ++k) {
            float v = __shfl(h1, k, 64);
            a2 = fmaf(W2[k * 64 + lane], v, a2);
        }
        float h2 = fmaxf(a2, 0.f);
        float o0 = B3[lane], o1 = B3[64 + lane];
        for (int k = 0; k < 64; ++k) {
            float v = __shfl(h2, k, 64);
            o0 = fmaf(W3[k * 128 + lane], v, o0);
            o1 = fmaf(W3[k * 128 + 64 + lane], v, o1);
        }
        m0 = fmaxf(m0, o0);
        m1 = fmaxf(m1, o1);
    }
    out[(size_t)qid * 128 + lane] = m0;
    out[(size_t)qid * 128 + 64 + lane] = m1;
}

// ---------- SA2 conv: one wave per query; feat=[x1(128), rel(6)] -> 128 -> 128 -> 256 ----------

__global__ __launch_bounds__(256) void sa2_conv(const float* __restrict__ pos1, const float* __restrict__ posq,
                                                const int* __restrict__ nbr, const int* __restrict__ cnt,
                                                const float* __restrict__ x1,
                                                const float* __restrict__ W1, const float* __restrict__ B1,
                                                const float* __restrict__ W2, const float* __restrict__ B2,
                                                const float* __restrict__ W3, const float* __restrict__ B3,
                                                float* __restrict__ out) {
    int lane = threadIdx.x & 63;
    int w = threadIdx.x >> 6;
    int qid = blockIdx.x * 4 + w;
    int b = qid / NS2_;
    float q[6];
#pragma unroll
    for (int d = 0; d < 6; ++d) q[d] = posq[(size_t)qid * 6 + d];
    int c = cnt[qid];
    float m0 = -INFINITY, m1 = -INFINITY, m2 = -INFINITY, m3 = -INFINITY;

    for (int n = 0; n < c; ++n) {
        int j = nbr[(size_t)qid * K_ + n];
        size_t row = (size_t)b * NS1_ + j;
        const float* xs = x1 + row * 128;
        float rel[6];
#pragma unroll
        for (int d = 0; d < 6; ++d) rel[d] = pos1[row * 6 + d] - q[d];
        float a0 = B1[lane], a1 = B1[64 + lane];
        for (int k = 0; k < 128; ++k) {
            float v = xs[k];
            a0 = fmaf(W1[k * 128 + lane], v, a0);
            a1 = fmaf(W1[k * 128 + 64 + lane], v, a1);
        }
#pragma unroll
        for (int d = 0; d < 6; ++d) {
            float v = rel[d];
            a0 = fmaf(W1[(128 + d) * 128 + lane], v, a0);
            a1 = fmaf(W1[(128 + d) * 128 + 64 + lane], v, a1);
        }
        float h1a = fmaxf(a0, 0.f), h1b = fmaxf(a1, 0.f);
        float c0 = B2[lane], c1 = B2[64 + lane];
        for (int k = 0; k < 64; ++k) {
            float v = __shfl(h1a, k, 64);
            c0 = fmaf(W2[k * 128 + lane], v, c0);
            c1 = fmaf(W2[k * 128 + 64 + lane], v, c1);
        }
        for (int k = 0; k < 64; ++k) {
            float v = __shfl(h1b, k, 64);
            c0 = fmaf(W2[(64 + k) * 128 + lane], v, c0);
            c1 = fmaf(W2[(64 + k) * 128 + 64 + lane], v, c1);
        }
        float h2a = fmaxf(c0, 0.f), h2b = fmaxf(c1, 0.f);
        float e0 = B3[lane], e1 = B3[64 + lane], e2 = B3[128 + lane], e3 = B3[192 + lane];
        for (int k = 0; k < 64; ++k) {
            float v = __shfl(h2a, k, 64);
            e0 = fmaf(W3[k * 256 + lane], v, e0);
            e1 = fmaf(W3[k * 256 + 64 + lane], v, e1);
            e2 = fmaf(W3[k * 256 + 128 + lane], v, e2);
            e3 = fmaf(W3[k * 256 + 192 + lane], v, e3);
        }
        for (int k = 0; k < 64; ++k) {
            float v = __shfl(h2b, k, 64);
            e0 = fmaf(W3[(64 + k) * 256 + lane], v, e0);
            e1 = fmaf(W3[(64 + k) * 256 + 64 + lane], v, e1);
            e2 = fmaf(W3[(64 + k) * 256 + 128 + lane], v, e2);
            e3 = fmaf(W3[(64 + k) * 256 + 192 + lane], v, e3);
        }
        m0 = fmaxf(m0, e0);
        m1 = fmaxf(m1, e1);
        m2 = fmaxf(m2, e2);
        m3 = fmaxf(m3, e3);
    }
    out[(size_t)qid * 256 + lane] = m0;
    out[(size_t)qid * 256 + 64 + lane] = m1;
    out[(size_t)qid * 256 + 128 + lane] = m2;
    out[(size_t)qid * 256 + 192 + lane] = m3;
}

// ---------- init g ----------

__global__ void init_g(unsigned* __restrict__ g) {
    g[blockIdx.x * 1024 + threadIdx.x] = 0u;
}

// ---------- MLP3 v2: wave = 4 queries register-blocked; weight float4 reused across queries ----------

__global__ __launch_bounds__(256, 1) void mlp3_kernel(const float* __restrict__ x2, const float* __restrict__ pos2,
                                                      const float* __restrict__ W0, const float* __restrict__ B0,
                                                      const float* __restrict__ W1, const float* __restrict__ B1,
                                                      const float* __restrict__ W2, const float* __restrict__ B2,
                                                      unsigned* __restrict__ g) {
    int lane = threadIdx.x & 63;
    int w = threadIdx.x >> 6;
    int qid0 = blockIdx.x * 16 + w * 4;  // 4 queries per wave, 16 per block
    int b = qid0 >> 9;                   // 512 queries per cloud

    float xr[4][4];
#pragma unroll
    for (int q = 0; q < 4; ++q)
#pragma unroll
        for (int j = 0; j < 4; ++j) xr[q][j] = x2[(size_t)(qid0 + q) * 256 + j * 64 + lane];

    // ---- L1: 262 -> 256, out channel = lane*4+u ----
    float a[4][4];
    {
        float4 bv = *(const float4*)&B0[lane * 4];
#pragma unroll
        for (int q = 0; q < 4; ++q) { a[q][0] = bv.x; a[q][1] = bv.y; a[q][2] = bv.z; a[q][3] = bv.w; }
    }
#pragma unroll
    for (int j = 0; j < 4; ++j) {
        for (int k2 = 0; k2 < 64; ++k2) {
            int k = j * 64 + k2;
            float4 wv = *(const float4*)&W0[(size_t)k * 256 + lane * 4];
#pragma unroll
            for (int q = 0; q < 4; ++q) {
                float v = __shfl(xr[q][j], k2, 64);
                a[q][0] = fmaf(wv.x, v, a[q][0]);
                a[q][1] = fmaf(wv.y, v, a[q][1]);
                a[q][2] = fmaf(wv.z, v, a[q][2]);
                a[q][3] = fmaf(wv.w, v, a[q][3]);
            }
        }
    }
#pragma unroll
    for (int d = 0; d < 6; ++d) {
        float4 wv = *(const float4*)&W0[(size_t)(256 + d) * 256 + lane * 4];
#pragma unroll
        for (int q = 0; q < 4; ++q) {
            float v = pos2[(size_t)(qid0 + q) * 6 + d];
            a[q][0] = fmaf(wv.x, v, a[q][0]);
            a[q][1] = fmaf(wv.y, v, a[q][1]);
            a[q][2] = fmaf(wv.z, v, a[q][2]);
            a[q][3] = fmaf(wv.w, v, a[q][3]);
        }
    }
    float h1[4][4];
#pragma unroll
    for (int q = 0; q < 4; ++q)
#pragma unroll
        for (int u = 0; u < 4; ++u) h1[q][u] = fmaxf(a[q][u], 0.f);

    // ---- L2: 256 -> 512, out channel = lane*8+u ----
    float c[4][8];
    {
        float4 b0 = *(const float4*)&B1[lane * 8];
        float4 b1 = *(const float4*)&B1[lane * 8 + 4];
#pragma unroll
        for (int q = 0; q < 4; ++q) {
            c[q][0] = b0.x; c[q][1] = b0.y; c[q][2] = b0.z; c[q][3] = b0.w;
            c[q][4] = b1.x; c[q][5] = b1.y; c[q][6] = b1.z; c[q][7] = b1.w;
        }
    }
    for (int l = 0; l < 64; ++l) {
#pragma unroll
        for (int r = 0; r < 4; ++r) {
            int k = l * 4 + r;
            float4 w0 = *(const float4*)&W1[(size_t)k * 512 + lane * 8];
            float4 w1 = *(const float4*)&W1[(size_t)k * 512 + lane * 8 + 4];
#pragma unroll
            for (int q = 0; q < 4; ++q) {
                float v = __shfl(h1[q][r], l, 64);
                c[q][0] = fmaf(w0.x, v, c[q][0]);
                c[q][1] = fmaf(w0.y, v, c[q][1]);
                c[q][2] = fmaf(w0.z, v, c[q][2]);
                c[q][3] = fmaf(w0.w, v, c[q][3]);
                c[q][4] = fmaf(w1.x, v, c[q][4]);
                c[q][5] = fmaf(w1.y, v, c[q][5]);
                c[q][6] = fmaf(w1.z, v, c[q][6]);
                c[q][7] = fmaf(w1.w, v, c[q][7]);
            }
        }
    }
    float h2[4][8];
#pragma unroll
    for (int q = 0; q < 4; ++q)
#pragma unroll
        for (int u = 0; u < 8; ++u) h2[q][u] = fmaxf(c[q][u], 0.f);

    // ---- L3: 512 -> 1024, out channel = lane*16+u ----
    float e[4][16];
#pragma unroll
    for (int jj = 0; jj < 4; ++jj) {
        float4 bv = *(const float4*)&B2[lane * 16 + jj * 4];
#pragma unroll
        for (int q = 0; q < 4; ++q) {
            e[q][jj * 4 + 0] = bv.x; e[q][jj * 4 + 1] = bv.y;
            e[q][jj * 4 + 2] = bv.z; e[q][jj * 4 + 3] = bv.w;
        }
    }
    for (int l = 0; l < 64; ++l) {
#pragma unroll
        for (int r = 0; r < 8; ++r) {
            int k = l * 8 + r;
            const float* wp = &W2[(size_t)k * 1024 + lane * 16];
            float4 w0 = *(const float4*)&wp[0];
            float4 w1 = *(const float4*)&wp[4];
            float4 w2 = *(const float4*)&wp[8];
            float4 w3 = *(const float4*)&wp[12];
#pragma unroll
            for (int q = 0; q < 4; ++q) {
                float v = __shfl(h2[q][r], l, 64);
                e[q][0]  = fmaf(w0.x, v, e[q][0]);
                e[q][1]  = fmaf(w0.y, v, e[q][1]);
                e[q][2]  = fmaf(w0.z, v, e[q][2]);
                e[q][3]  = fmaf(w0.w, v, e[q][3]);
                e[q][4]  = fmaf(w1.x, v, e[q][4]);
                e[q][5]  = fmaf(w1.y, v, e[q][5]);
                e[q][6]  = fmaf(w1.z, v, e[q][6]);
                e[q][7]  = fmaf(w1.w, v, e[q][7]);
                e[q][8]  = fmaf(w2.x, v, e[q][8]);
                e[q][9]  = fmaf(w2.y, v, e[q][9]);
                e[q][10] = fmaf(w2.z, v, e[q][10]);
                e[q][11] = fmaf(w2.w, v, e[q][11]);
                e[q][12] = fmaf(w3.x, v, e[q][12]);
                e[q][13] = fmaf(w3.y, v, e[q][13]);
                e[q][14] = fmaf(w3.z, v, e[q][14]);
                e[q][15] = fmaf(w3.w, v, e[q][15]);
            }
        }
    }
#pragma unroll
    for (int u = 0; u < 16; ++u) {
        float m = fmaxf(fmaxf(e[0][u], e[1][u]), fmaxf(e[2][u], e[3][u]));
        atomicMax(&g[b * 1024 + lane * 16 + u], mapf(m));
    }
}

// ---------- MLP4: 1024 -> 512 (relu) -> 512; one block per b ----------

__global__ __launch_bounds__(512) void mlp4_kernel(const unsigned* __restrict__ g,
                                                   const float* __restrict__ W0, const float* __restrict__ B0,
                                                   const float* __restrict__ W1, const float* __restrict__ B1,
                                                   float* __restrict__ out) {
    int b = blockIdx.x;
    int c = threadIdx.x;
    __shared__ float h[512];
    float a = B0[c];
    for (int k = 0; k < 1024; ++k) {
        float v = unmapf(g[b * 1024 + k]);
        a = fmaf(v, W0[k * 512 + c], a);
    }
    h[c] = fmaxf(a, 0.f);
    __syncthreads();
    float o = B1[c];
    for (int k = 0; k < 512; ++k) o = fmaf(h[k], W1[k * 512 + c], o);
    out[(size_t)b * 512 + c] = o;
}

// ---------- launch ----------

extern "C" void kernel_launch(void* const* d_in, const int* in_sizes, int n_in,
                              void* d_out, int out_size, void* d_ws, size_t ws_size,
                              hipStream_t stream) {
    const float* pos = (const float*)d_in[0];  // [B*N, 6]
    const float* w1_0 = (const float*)d_in[3];
    const float* b1_0 = (const float*)d_in[4];
    const float* w1_1 = (const float*)d_in[5];
    const float* b1_1 = (const float*)d_in[6];
    const float* w1_2 = (const float*)d_in[7];
    const float* b1_2 = (const float*)d_in[8];
    const float* w2_0 = (const float*)d_in[9];
    const float* b2_0 = (const float*)d_in[10];
    const float* w2_1 = (const float*)d_in[11];
    const float* b2_1 = (const float*)d_in[12];
    const float* w2_2 = (const float*)d_in[13];
    const float* b2_2 = (const float*)d_in[14];
    const float* w3_0 = (const float*)d_in[15];
    const float* b3_0 = (const float*)d_in[16];
    const float* w3_1 = (const float*)d_in[17];
    const float* b3_1 = (const float*)d_in[18];
    const float* w3_2 = (const float*)d_in[19];
    const float* b3_2 = (const float*)d_in[20];
    const float* w4_0 = (const float*)d_in[21];
    const float* b4_0 = (const float*)d_in[22];
    const float* w4_1 = (const float*)d_in[23];
    const float* b4_1 = (const float*)d_in[24];
    float* out = (float*)d_out;

    char* ws = (char*)d_ws;
    size_t off = 0;
    float* pos1 = (float*)(ws + off);  off += (size_t)B_ * NS1_ * 6 * 4;
    int* nbr1 = (int*)(ws + off);      off += (size_t)B_ * NS1_ * K_ * 4;
    int* cnt1 = (int*)(ws + off);      off += (size_t)B_ * NS1_ * 4;
    float* x1 = (float*)(ws + off);    off += (size_t)B_ * NS1_ * 128 * 4;
    float* pos2 = (float*)(ws + off);  off += (size_t)B_ * NS2_ * 6 * 4;
    int* nbr2 = (int*)(ws + off);      off += (size_t)B_ * NS2_ * K_ * 4;
    int* cnt2 = (int*)(ws + off);      off += (size_t)B_ * NS2_ * 4;
    float* x2 = (float*)(ws + off);    off += (size_t)B_ * NS2_ * 256 * 4;
    unsigned* g = (unsigned*)(ws + off); off += (size_t)B_ * 1024 * 4;

    const float r2_1 = (float)(0.2 * 0.2);
    const float r2_2 = (float)(0.4 * 0.4);

    // SA1
    fps_kernel<N_, NS1_><<<B_, 256, 0, stream>>>(pos, pos1);
    ball_kernel<<<(B_ * NS1_) / 64, 64, 0, stream>>>(pos, pos1, nbr1, cnt1, N_, NS1_, r2_1);
    sa1_conv<<<(B_ * NS1_) / 4, 256, 0, stream>>>(pos, pos1, nbr1, cnt1,
                                                  w1_0, b1_0, w1_1, b1_1, w1_2, b1_2, x1, N_, NS1_);
    // SA2
    fps_kernel<NS1_, NS2_><<<B_, 256, 0, stream>>>(pos1, pos2);
    ball_kernel<<<(B_ * NS2_) / 64, 64, 0, stream>>>(pos1, pos2, nbr2, cnt2, NS1_, NS2_, r2_2);
    sa2_conv<<<(B_ * NS2_) / 4, 256, 0, stream>>>(pos1, pos2, nbr2, cnt2, x1,
                                                  w2_0, b2_0, w2_1, b2_1, w2_2, b2_2, x2);
    // MLP3 + global max
    init_g<<<B_, 1024, 0, stream>>>(g);
    mlp3_kernel<<<(B_ * NS2_) / 16, 256, 0, stream>>>(x2, pos2, w3_0, b3_0, w3_1, b3_1, w3_2, b3_2, g);
    // MLP4
    mlp4_kernel<<<B_, 512, 0, stream>>>(g, w4_0, b4_0, w4_1, b4_1, out);
}

// Round 7
// 3154.015 us; speedup vs baseline: 2.9105x; 1.0276x over previous
//
#include <hip/hip_runtime.h>
#include <math.h>

#define B_ 8
#define N_ 4096
#define D_ 6
#define K_ 64
#define NS1_ 2048
#define NS2_ 512

// ---------- helpers ----------

__device__ __forceinline__ float dist2_rn(const float* __restrict__ a, const float* __restrict__ q) {
    // exact np semantics: sequential sum of (a-b)^2, round-to-nearest each op, no fma
    float s = 0.f;
#pragma unroll
    for (int d = 0; d < 6; ++d) {
        float diff = __fsub_rn(a[d], q[d]);
        s = __fadd_rn(s, __fmul_rn(diff, diff));
    }
    return s;
}

__device__ __forceinline__ unsigned mapf(float x) {
    unsigned u = __float_as_uint(x);
    return (u & 0x80000000u) ? ~u : (u | 0x80000000u);
}
__device__ __forceinline__ float unmapf(unsigned u) {
    return __uint_as_float((u & 0x80000000u) ? (u & 0x7FFFFFFFu) : ~u);
}

// DPP move on a f64 key (two 32-bit DPPs); invalid lanes keep own value (identity for max).
// Keys are non-negative doubles bitwise == (d2_fp32_bits<<32 | ~idx): u64 order == f64 order.
template <int CTRL>
__device__ __forceinline__ double dppd(double k) {
    int lo = __double2loint(k), hi = __double2hiint(k);
    int nlo = __builtin_amdgcn_update_dpp(lo, lo, CTRL, 0xF, 0xF, false);
    int nhi = __builtin_amdgcn_update_dpp(hi, hi, CTRL, 0xF, 0xF, false);
    return __hiloint2double(nhi, nlo);
}

// ---------- FPS v7: pk-f32 update pairs + f64-fmax DPP ladder ----------
// contract(off): plain float ops are exact rn, no fma contraction -> bit-identical selection
// to np's sequential chain. Argmax key = hi:d2 bits, lo:~gidx (first-occurrence tie-break).

template <int NP, int NS, bool ZG>
__global__ __launch_bounds__(256, 1) void fps_kernel(const float* __restrict__ pos,
                                                     float* __restrict__ posq,
                                                     unsigned* __restrict__ g) {
#pragma clang fp contract(off)
    constexpr int NT = 256;
    constexpr int P = NP / NT;
    constexpr int HP = P / 2;
    int b = blockIdx.x, t = threadIdx.x;
    int lane = t & 63, w = t >> 6;
    const float* p = pos + (size_t)b * NP * 6;
    __shared__ float spos[NP * 6];   // row-major [j*6+d]
    __shared__ int sidx[NS];
    __shared__ double part[2][4];

    // stage into LDS, coalesced float4
    {
        const float4* src = (const float4*)p;
        float4* dst = (float4*)spos;
        for (int e = t; e < NP * 6 / 4; e += NT) dst[e] = src[e];
    }
    if (t == 0) sidx[0] = 0;
    __syncthreads();

    // this thread's points in register pairs: pair j = points t+NT*(2j), t+NT*(2j+1)
    float2 px2[HP][6];
#pragma unroll
    for (int j = 0; j < HP; ++j)
#pragma unroll
        for (int d = 0; d < 6; ++d) {
            px2[j][d].x = spos[(t + NT * (2 * j)) * 6 + d];
            px2[j][d].y = spos[(t + NT * (2 * j + 1)) * 6 + d];
        }

    // first sample = point 0
    float cx[6];
#pragma unroll
    for (int d = 0; d < 6; ++d) cx[d] = spos[d];

    float2 mind2[HP];
    float runv = -1.f;
    int runj = 0;
#pragma unroll
    for (int j = 0; j < HP; ++j) {
        float2 d2; d2.x = 0.f; d2.y = 0.f;
#pragma unroll
        for (int d = 0; d < 6; ++d) {
            float dfx = px2[j][d].x - cx[d];
            float dfy = px2[j][d].y - cx[d];
            d2.x = d2.x + dfx * dfx;
            d2.y = d2.y + dfy * dfy;
        }
        mind2[j] = d2;
        if (d2.x > runv) { runv = d2.x; runj = t + NT * (2 * j); }      // ascending gidx:
        if (d2.y > runv) { runv = d2.y; runj = t + NT * (2 * j + 1); }  // strict > keeps lowest
    }

    for (int s = 1; s < NS; ++s) {
        // wave-level argmax reduce via f64-fmax DPP ladder
        double key = __hiloint2double((int)__float_as_uint(runv), (int)(unsigned)(~runj));
        key = fmax(key, dppd<0x111>(key));  // row_shr:1
        key = fmax(key, dppd<0x112>(key));  // row_shr:2
        key = fmax(key, dppd<0x114>(key));  // row_shr:4
        key = fmax(key, dppd<0x118>(key));  // row_shr:8
        key = fmax(key, dppd<0x142>(key));  // row_bcast:15
        key = fmax(key, dppd<0x143>(key));  // row_bcast:31 -> lane 63 = wave max
        if (lane == 63) part[s & 1][w] = key;
        __syncthreads();
        // every wave redundantly reduces the 4 partials (2 DPP levels, lanes 0..3)
        double kk = part[s & 1][lane & 3];
        kk = fmax(kk, dppd<0x111>(kk));
        kk = fmax(kk, dppd<0x112>(kk));   // lane 3 = max of partials 0..3
        int nx = ~__builtin_amdgcn_readlane(__double2loint(kk), 3);
        if (t == 0) sidx[s] = nx;  // off critical path; consumed only at the end

        // broadcast-read new center coords (nx uniform)
        const float2* sv2 = (const float2*)spos;
        float2 ca = sv2[nx * 3], cb = sv2[nx * 3 + 1], cc = sv2[nx * 3 + 2];
        cx[0] = ca.x; cx[1] = ca.y; cx[2] = cb.x; cx[3] = cb.y; cx[4] = cc.x; cx[5] = cc.y;

        // fused update + local argmax (pairwise -> v_pk_{add,mul}_f32 candidates)
        runv = -1.f;
        runj = 0;
#pragma unroll
        for (int j = 0; j < HP; ++j) {
            float2 d2; d2.x = 0.f; d2.y = 0.f;
#pragma unroll
            for (int d = 0; d < 6; ++d) {
                float dfx = px2[j][d].x - cx[d];
                float dfy = px2[j][d].y - cx[d];
                d2.x = d2.x + dfx * dfx;
                d2.y = d2.y + dfy * dfy;
            }
            float mx = fminf(mind2[j].x, d2.x);
            float my = fminf(mind2[j].y, d2.y);
            mind2[j].x = mx;
            mind2[j].y = my;
            if (mx > runv) { runv = mx; runj = t + NT * (2 * j); }
            if (my > runv) { runv = my; runj = t + NT * (2 * j + 1); }
        }
    }
    __syncthreads();
    // write posq once, from LDS
    for (int s2 = t; s2 < NS; s2 += NT) {
        int nx = sidx[s2];
#pragma unroll
        for (int d = 0; d < 6; ++d) posq[((size_t)b * NS + s2) * 6 + d] = spos[nx * 6 + d];
    }
    if (ZG) {  // fold init_g into fps2: zero the global-max buffer (consumed by mlp3 later)
        for (int e = t; e < 1024; e += NT) g[b * 1024 + e] = 0u;
    }
}

// ---------- ball query: one thread per query, block=64, interleaved LDS top-K ----------

__global__ __launch_bounds__(64) void ball_kernel(const float* __restrict__ pos, const float* __restrict__ posq,
                                                  int* __restrict__ nbr, int* __restrict__ cnt,
                                                  int N, int nq, float r2) {
    __shared__ float sd[K_ * 64];
    __shared__ int si[K_ * 64];
    int tid = threadIdx.x;
    int qid = blockIdx.x * 64 + tid;
    int b = qid / nq;
    const float* p = pos + (size_t)b * N * 6;
    float q[6];
#pragma unroll
    for (int d = 0; d < 6; ++d) q[d] = posq[(size_t)qid * 6 + d];

    int n = 0;
    for (int j = 0; j < N; ++j) {
        float d2 = dist2_rn(p + (size_t)j * 6, q);
        if (d2 <= r2) {
            if (n < K_) {
                int i = n++;
                while (i > 0 && sd[(i - 1) * 64 + tid] > d2) {
                    sd[i * 64 + tid] = sd[(i - 1) * 64 + tid];
                    si[i * 64 + tid] = si[(i - 1) * 64 + tid];
                    --i;
                }
                sd[i * 64 + tid] = d2;
                si[i * 64 + tid] = j;
            } else if (d2 < sd[(K_ - 1) * 64 + tid]) {
                int i = K_ - 1;
                while (i > 0 && sd[(i - 1) * 64 + tid] > d2) {
                    sd[i * 64 + tid] = sd[(i - 1) * 64 + tid];
                    si[i * 64 + tid] = si[(i - 1) * 64 + tid];
                    --i;
                }
                sd[i * 64 + tid] = d2;
                si[i * 64 + tid] = j;
            }
        }
    }
    cnt[qid] = n;
    for (int i = 0; i < n; ++i) nbr[(size_t)qid * K_ + i] = si[i * 64 + tid];
}

// ---------- SA1 conv: one wave per query; MLP 6->64->64->128, max over valid neighbors ----------

__global__ __launch_bounds__(256) void sa1_conv(const float* __restrict__ pos, const float* __restrict__ posq,
                                                const int* __restrict__ nbr, const int* __restrict__ cnt,
                                                const float* __restrict__ W1, const float* __restrict__ B1,
                                                const float* __restrict__ W2, const float* __restrict__ B2,
                                                const float* __restrict__ W3, const float* __restrict__ B3,
                                                float* __restrict__ out, int N, int nq) {
    int lane = threadIdx.x & 63;
    int w = threadIdx.x >> 6;
    int qid = blockIdx.x * 4 + w;
    int b = qid / nq;
    const float* p = pos + (size_t)b * N * 6;
    float q[6];
#pragma unroll
    for (int d = 0; d < 6; ++d) q[d] = posq[(size_t)qid * 6 + d];
    int c = cnt[qid];
    float m0 = -INFINITY, m1 = -INFINITY;

    for (int n = 0; n < c; ++n) {
        int j = nbr[(size_t)qid * K_ + n];
        float rel[6];
#pragma unroll
        for (int d = 0; d < 6; ++d) rel[d] = p[(size_t)j * 6 + d] - q[d];
        float a = B1[lane];
#pragma unroll
        for (int d = 0; d < 6; ++d) a = fmaf(W1[d * 64 + lane], rel[d], a);
        float h1 = fmaxf(a, 0.f);
        float a2 = B2[lane];
        for (int k = 0; k < 64; ++k) {
            float v = __shfl(h1, k, 64);
            a2 = fmaf(W2[k * 64 + lane], v, a2);
        }
        float h2 = fmaxf(a2, 0.f);
        float o0 = B3[lane], o1 = B3[64 + lane];
        for (int k = 0; k < 64; ++k) {
            float v = __shfl(h2, k, 64);
            o0 = fmaf(W3[k * 128 + lane], v, o0);
            o1 = fmaf(W3[k * 128 + 64 + lane], v, o1);
        }
        m0 = fmaxf(m0, o0);
        m1 = fmaxf(m1, o1);
    }
    out[(size_t)qid * 128 + lane] = m0;
    out[(size_t)qid * 128 + 64 + lane] = m1;
}

// ---------- SA2 conv: one wave per query; feat=[x1(128), rel(6)] -> 128 -> 128 -> 256 ----------

__global__ __launch_bounds__(256) void sa2_conv(const float* __restrict__ pos1, const float* __restrict__ posq,
                                                const int* __restrict__ nbr, const int* __restrict__ cnt,
                                                const float* __restrict__ x1,
                                                const float* __restrict__ W1, const float* __restrict__ B1,
                                                const float* __restrict__ W2, const float* __restrict__ B2,
                                                const float* __restrict__ W3, const float* __restrict__ B3,
                                                float* __restrict__ out) {
    int lane = threadIdx.x & 63;
    int w = threadIdx.x >> 6;
    int qid = blockIdx.x * 4 + w;
    int b = qid / NS2_;
    float q[6];
#pragma unroll
    for (int d = 0; d < 6; ++d) q[d] = posq[(size_t)qid * 6 + d];
    int c = cnt[qid];
    float m0 = -INFINITY, m1 = -INFINITY, m2 = -INFINITY, m3 = -INFINITY;

    for (int n = 0; n < c; ++n) {
        int j = nbr[(size_t)qid * K_ + n];
        size_t row = (size_t)b * NS1_ + j;
        const float* xs = x1 + row * 128;
        float rel[6];
#pragma unroll
        for (int d = 0; d < 6; ++d) rel[d] = pos1[row * 6 + d] - q[d];
        float a0 = B1[lane], a1 = B1[64 + lane];
        for (int k = 0; k < 128; ++k) {
            float v = xs[k];
            a0 = fmaf(W1[k * 128 + lane], v, a0);
            a1 = fmaf(W1[k * 128 + 64 + lane], v, a1);
        }
#pragma unroll
        for (int d = 0; d < 6; ++d) {
            float v = rel[d];
            a0 = fmaf(W1[(128 + d) * 128 + lane], v, a0);
            a1 = fmaf(W1[(128 + d) * 128 + 64 + lane], v, a1);
        }
        float h1a = fmaxf(a0, 0.f), h1b = fmaxf(a1, 0.f);
        float c0 = B2[lane], c1 = B2[64 + lane];
        for (int k = 0; k < 64; ++k) {
            float v = __shfl(h1a, k, 64);
            c0 = fmaf(W2[k * 128 + lane], v, c0);
            c1 = fmaf(W2[k * 128 + 64 + lane], v, c1);
        }
        for (int k = 0; k < 64; ++k) {
            float v = __shfl(h1b, k, 64);
            c0 = fmaf(W2[(64 + k) * 128 + lane], v, c0);
            c1 = fmaf(W2[(64 + k) * 128 + 64 + lane], v, c1);
        }
        float h2a = fmaxf(c0, 0.f), h2b = fmaxf(c1, 0.f);
        float e0 = B3[lane], e1 = B3[64 + lane], e2 = B3[128 + lane], e3 = B3[192 + lane];
        for (int k = 0; k < 64; ++k) {
            float v = __shfl(h2a, k, 64);
            e0 = fmaf(W3[k * 256 + lane], v, e0);
            e1 = fmaf(W3[k * 256 + 64 + lane], v, e1);
            e2 = fmaf(W3[k * 256 + 128 + lane], v, e2);
            e3 = fmaf(W3[k * 256 + 192 + lane], v, e3);
        }
        for (int k = 0; k < 64; ++k) {
            float v = __shfl(h2b, k, 64);
            e0 = fmaf(W3[(64 + k) * 256 + lane], v, e0);
            e1 = fmaf(W3[(64 + k) * 256 + 64 + lane], v, e1);
            e2 = fmaf(W3[(64 + k) * 256 + 128 + lane], v, e2);
            e3 = fmaf(W3[(64 + k) * 256 + 192 + lane], v, e3);
        }
        m0 = fmaxf(m0, e0);
        m1 = fmaxf(m1, e1);
        m2 = fmaxf(m2, e2);
        m3 = fmaxf(m3, e3);
    }
    out[(size_t)qid * 256 + lane] = m0;
    out[(size_t)qid * 256 + 64 + lane] = m1;
    out[(size_t)qid * 256 + 128 + lane] = m2;
    out[(size_t)qid * 256 + 192 + lane] = m3;
}

// ---------- MLP3 v2: wave = 4 queries register-blocked; weight float4 reused across queries ----------

__global__ __launch_bounds__(256, 1) void mlp3_kernel(const float* __restrict__ x2, const float* __restrict__ pos2,
                                                      const float* __restrict__ W0, const float* __restrict__ B0,
                                                      const float* __restrict__ W1, const float* __restrict__ B1,
                                                      const float* __restrict__ W2, const float* __restrict__ B2,
                                                      unsigned* __restrict__ g) {
    int lane = threadIdx.x & 63;
    int w = threadIdx.x >> 6;
    int qid0 = blockIdx.x * 16 + w * 4;  // 4 queries per wave, 16 per block
    int b = qid0 >> 9;                   // 512 queries per cloud

    float xr[4][4];
#pragma unroll
    for (int q = 0; q < 4; ++q)
#pragma unroll
        for (int j = 0; j < 4; ++j) xr[q][j] = x2[(size_t)(qid0 + q) * 256 + j * 64 + lane];

    // ---- L1: 262 -> 256, out channel = lane*4+u ----
    float a[4][4];
    {
        float4 bv = *(const float4*)&B0[lane * 4];
#pragma unroll
        for (int q = 0; q < 4; ++q) { a[q][0] = bv.x; a[q][1] = bv.y; a[q][2] = bv.z; a[q][3] = bv.w; }
    }
#pragma unroll
    for (int j = 0; j < 4; ++j) {
        for (int k2 = 0; k2 < 64; ++k2) {
            int k = j * 64 + k2;
            float4 wv = *(const float4*)&W0[(size_t)k * 256 + lane * 4];
#pragma unroll
            for (int q = 0; q < 4; ++q) {
                float v = __shfl(xr[q][j], k2, 64);
                a[q][0] = fmaf(wv.x, v, a[q][0]);
                a[q][1] = fmaf(wv.y, v, a[q][1]);
                a[q][2] = fmaf(wv.z, v, a[q][2]);
                a[q][3] = fmaf(wv.w, v, a[q][3]);
            }
        }
    }
#pragma unroll
    for (int d = 0; d < 6; ++d) {
        float4 wv = *(const float4*)&W0[(size_t)(256 + d) * 256 + lane * 4];
#pragma unroll
        for (int q = 0; q < 4; ++q) {
            float v = pos2[(size_t)(qid0 + q) * 6 + d];
            a[q][0] = fmaf(wv.x, v, a[q][0]);
            a[q][1] = fmaf(wv.y, v, a[q][1]);
            a[q][2] = fmaf(wv.z, v, a[q][2]);
            a[q][3] = fmaf(wv.w, v, a[q][3]);
        }
    }
    float h1[4][4];
#pragma unroll
    for (int q = 0; q < 4; ++q)
#pragma unroll
        for (int u = 0; u < 4; ++u) h1[q][u] = fmaxf(a[q][u], 0.f);

    // ---- L2: 256 -> 512, out channel = lane*8+u ----
    float c[4][8];
    {
        float4 b0 = *(const float4*)&B1[lane * 8];
        float4 b1 = *(const float4*)&B1[lane * 8 + 4];
#pragma unroll
        for (int q = 0; q < 4; ++q) {
            c[q][0] = b0.x; c[q][1] = b0.y; c[q][2] = b0.z; c[q][3] = b0.w;
            c[q][4] = b1.x; c[q][5] = b1.y; c[q][6] = b1.z; c[q][7] = b1.w;
        }
    }
    for (int l = 0; l < 64; ++l) {
#pragma unroll
        for (int r = 0; r < 4; ++r) {
            int k = l * 4 + r;
            float4 w0 = *(const float4*)&W1[(size_t)k * 512 + lane * 8];
            float4 w1 = *(const float4*)&W1[(size_t)k * 512 + lane * 8 + 4];
#pragma unroll
            for (int q = 0; q < 4; ++q) {
                float v = __shfl(h1[q][r], l, 64);
                c[q][0] = fmaf(w0.x, v, c[q][0]);
                c[q][1] = fmaf(w0.y, v, c[q][1]);
                c[q][2] = fmaf(w0.z, v, c[q][2]);
                c[q][3] = fmaf(w0.w, v, c[q][3]);
                c[q][4] = fmaf(w1.x, v, c[q][4]);
                c[q][5] = fmaf(w1.y, v, c[q][5]);
                c[q][6] = fmaf(w1.z, v, c[q][6]);
                c[q][7] = fmaf(w1.w, v, c[q][7]);
            }
        }
    }
    float h2[4][8];
#pragma unroll
    for (int q = 0; q < 4; ++q)
#pragma unroll
        for (int u = 0; u < 8; ++u) h2[q][u] = fmaxf(c[q][u], 0.f);

    // ---- L3: 512 -> 1024, out channel = lane*16+u ----
    float e[4][16];
#pragma unroll
    for (int jj = 0; jj < 4; ++jj) {
        float4 bv = *(const float4*)&B2[lane * 16 + jj * 4];
#pragma unroll
        for (int q = 0; q < 4; ++q) {
            e[q][jj * 4 + 0] = bv.x; e[q][jj * 4 + 1] = bv.y;
            e[q][jj * 4 + 2] = bv.z; e[q][jj * 4 + 3] = bv.w;
        }
    }
    for (int l = 0; l < 64; ++l) {
#pragma unroll
        for (int r = 0; r < 8; ++r) {
            int k = l * 8 + r;
            const float* wp = &W2[(size_t)k * 1024 + lane * 16];
            float4 w0 = *(const float4*)&wp[0];
            float4 w1 = *(const float4*)&wp[4];
            float4 w2 = *(const float4*)&wp[8];
            float4 w3 = *(const float4*)&wp[12];
#pragma unroll
            for (int q = 0; q < 4; ++q) {
                float v = __shfl(h2[q][r], l, 64);
                e[q][0]  = fmaf(w0.x, v, e[q][0]);
                e[q][1]  = fmaf(w0.y, v, e[q][1]);
                e[q][2]  = fmaf(w0.z, v, e[q][2]);
                e[q][3]  = fmaf(w0.w, v, e[q][3]);
                e[q][4]  = fmaf(w1.x, v, e[q][4]);
                e[q][5]  = fmaf(w1.y, v, e[q][5]);
                e[q][6]  = fmaf(w1.z, v, e[q][6]);
                e[q][7]  = fmaf(w1.w, v, e[q][7]);
                e[q][8]  = fmaf(w2.x, v, e[q][8]);
                e[q][9]  = fmaf(w2.y, v, e[q][9]);
                e[q][10] = fmaf(w2.z, v, e[q][10]);
                e[q][11] = fmaf(w2.w, v, e[q][11]);
                e[q][12] = fmaf(w3.x, v, e[q][12]);
                e[q][13] = fmaf(w3.y, v, e[q][13]);
                e[q][14] = fmaf(w3.z, v, e[q][14]);
                e[q][15] = fmaf(w3.w, v, e[q][15]);
            }
        }
    }
#pragma unroll
    for (int u = 0; u < 16; ++u) {
        float m = fmaxf(fmaxf(e[0][u], e[1][u]), fmaxf(e[2][u], e[3][u]));
        atomicMax(&g[b * 1024 + lane * 16 + u], mapf(m));
    }
}

// ---------- MLP4: 1024 -> 512 (relu) -> 512; one block per b ----------

__global__ __launch_bounds__(512) void mlp4_kernel(const unsigned* __restrict__ g,
                                                   const float* __restrict__ W0, const float* __restrict__ B0,
                                                   const float* __restrict__ W1, const float* __restrict__ B1,
                                                   float* __restrict__ out) {
    int b = blockIdx.x;
    int c = threadIdx.x;
    __shared__ float h[512];
    float a = B0[c];
    for (int k = 0; k < 1024; ++k) {
        float v = unmapf(g[b * 1024 + k]);
        a = fmaf(v, W0[k * 512 + c], a);
    }
    h[c] = fmaxf(a, 0.f);
    __syncthreads();
    float o = B1[c];
    for (int k = 0; k < 512; ++k) o = fmaf(h[k], W1[k * 512 + c], o);
    out[(size_t)b * 512 + c] = o;
}

// ---------- launch ----------

extern "C" void kernel_launch(void* const* d_in, const int* in_sizes, int n_in,
                              void* d_out, int out_size, void* d_ws, size_t ws_size,
                              hipStream_t stream) {
    const float* pos = (const float*)d_in[0];  // [B*N, 6]
    const float* w1_0 = (const float*)d_in[3];
    const float* b1_0 = (const float*)d_in[4];
    const float* w1_1 = (const float*)d_in[5];
    const float* b1_1 = (const float*)d_in[6];
    const float* w1_2 = (const float*)d_in[7];
    const float* b1_2 = (const float*)d_in[8];
    const float* w2_0 = (const float*)d_in[9];
    const float* b2_0 = (const float*)d_in[10];
    const float* w2_1 = (const float*)d_in[11];
    const float* b2_1 = (const float*)d_in[12];
    const float* w2_2 = (const float*)d_in[13];
    const float* b2_2 = (const float*)d_in[14];
    const float* w3_0 = (const float*)d_in[15];
    const float* b3_0 = (const float*)d_in[16];
    const float* w3_1 = (const float*)d_in[17];
    const float* b3_1 = (const float*)d_in[18];
    const float* w3_2 = (const float*)d_in[19];
    const float* b3_2 = (const float*)d_in[20];
    const float* w4_0 = (const float*)d_in[21];
    const float* b4_0 = (const float*)d_in[22];
    const float* w4_1 = (const float*)d_in[23];
    const float* b4_1 = (const float*)d_in[24];
    float* out = (float*)d_out;

    char* ws = (char*)d_ws;
    size_t off = 0;
    float* pos1 = (float*)(ws + off);  off += (size_t)B_ * NS1_ * 6 * 4;
    int* nbr1 = (int*)(ws + off);      off += (size_t)B_ * NS1_ * K_ * 4;
    int* cnt1 = (int*)(ws + off);      off += (size_t)B_ * NS1_ * 4;
    float* x1 = (float*)(ws + off);    off += (size_t)B_ * NS1_ * 128 * 4;
    float* pos2 = (float*)(ws + off);  off += (size_t)B_ * NS2_ * 6 * 4;
    int* nbr2 = (int*)(ws + off);      off += (size_t)B_ * NS2_ * K_ * 4;
    int* cnt2 = (int*)(ws + off);      off += (size_t)B_ * NS2_ * 4;
    float* x2 = (float*)(ws + off);    off += (size_t)B_ * NS2_ * 256 * 4;
    unsigned* g = (unsigned*)(ws + off); off += (size_t)B_ * 1024 * 4;

    const float r2_1 = (float)(0.2 * 0.2);
    const float r2_2 = (float)(0.4 * 0.4);

    // SA1
    fps_kernel<N_, NS1_, false><<<B_, 256, 0, stream>>>(pos, pos1, nullptr);
    ball_kernel<<<(B_ * NS1_) / 64, 64, 0, stream>>>(pos, pos1, nbr1, cnt1, N_, NS1_, r2_1);
    sa1_conv<<<(B_ * NS1_) / 4, 256, 0, stream>>>(pos, pos1, nbr1, cnt1,
                                                  w1_0, b1_0, w1_1, b1_1, w1_2, b1_2, x1, N_, NS1_);
    // SA2 (fps2 also zeroes g for mlp3)
    fps_kernel<NS1_, NS2_, true><<<B_, 256, 0, stream>>>(pos1, pos2, g);
    ball_kernel<<<(B_ * NS2_) / 64, 64, 0, stream>>>(pos1, pos2, nbr2, cnt2, NS1_, NS2_, r2_2);
    sa2_conv<<<(B_ * NS2_) / 4, 256, 0, stream>>>(pos1, pos2, nbr2, cnt2, x1,
                                                  w2_0, b2_0, w2_1, b2_1, w2_2, b2_2, x2);
    // MLP3 + global max
    mlp3_kernel<<<(B_ * NS2_) / 16, 256, 0, stream>>>(x2, pos2, w3_0, b3_0, w3_1, b3_1, w3_2, b3_2, g);
    // MLP4
    mlp4_kernel<<<B_, 512, 0, stream>>>(g, w4_0, b4_0, w4_1, b4_1, out);
}